// Round 13
// baseline (1146.770 us; speedup 1.0000x reference)
//
#include <hip/hip_runtime.h>

#define B_ 8
#define CI 64
#define CO 64
#define H_ 256
#define W_ 256
#define EPS_ 1e-5f

#define SELU_SCALE 1.0507009873554805f
#define SELU_SA    1.7580993408473766f

typedef __attribute__((ext_vector_type(8))) short short8;
typedef __attribute__((ext_vector_type(4))) float f32x4;
typedef unsigned int u32;

__device__ __forceinline__ unsigned short f2bf(float f) {
    unsigned int u = __float_as_uint(f);
    u = (u + 0x7fffu + ((u >> 16) & 1u)) >> 16;
    return (unsigned short)u;
}
__device__ __forceinline__ float bf2f(unsigned short h) {
    return __uint_as_float(((unsigned)h) << 16);
}
__device__ __forceinline__ float selu_f(float u) {
    return (u > 0.f) ? SELU_SCALE * u : SELU_SA * (__expf(u) - 1.f);
}
__device__ __forceinline__ void gload_lds16(const void* g, void* l) {
    __builtin_amdgcn_global_load_lds(
        (const __attribute__((address_space(1))) u32*)g,
        (__attribute__((address_space(3))) u32*)l, 16, 0, 0);
}

// ===========================================================================
// Weight prepass (unchanged).
// blocks 0..71: wedge[wid][pos][ci4][co][j] fp32 (0=bl 1=br 2=tl 3=tr
//               4=bot 5=top 6=left 7=right)
// blocks 72..80: wpre[pos][co][ci ^ ((co&7)<<3)] bf16 from w_int
// ===========================================================================
__global__ __launch_bounds__(256) void prepass_weights(
    const float* __restrict__ w_int,
    const float* __restrict__ w_bl, const float* __restrict__ w_br,
    const float* __restrict__ w_tl, const float* __restrict__ w_tr,
    const float* __restrict__ w_bot, const float* __restrict__ w_top,
    const float* __restrict__ w_left, const float* __restrict__ w_right,
    unsigned short* __restrict__ wpre, float* __restrict__ wedge)
{
    const int blk = blockIdx.x, t = threadIdx.x;
    if (blk < 72) {
        const int wid = blk / 9, pos = blk % 9;
        const float* src = (wid == 0) ? w_bl : (wid == 1) ? w_br
                         : (wid == 2) ? w_tl : (wid == 3) ? w_tr
                         : (wid == 4) ? w_bot : (wid == 5) ? w_top
                         : (wid == 6) ? w_left : w_right;
        float* dst = wedge + (size_t)blk * 4096;
        for (int k = 0; k < 16; ++k) {
            const int lin = k * 256 + t;        // [ci4][co][j]
            const int c4  = lin >> 8;
            const int co  = (lin >> 2) & 63;
            const int j   = lin & 3;
            const int ci  = c4 * 4 + j;
            dst[lin] = src[(co * 64 + ci) * 9 + pos];
        }
    } else {
        const int pos = blk - 72;
        for (int k = 0; k < 16; ++k) {
            const int lin = k * 256 + t;
            const int co = lin >> 6, cip = lin & 63;
            const int ci = cip ^ ((co & 7) << 3);
            wpre[pos * 4096 + lin] = f2bf(w_int[(co * 64 + ci) * 9 + pos]);
        }
    }
}

// ===========================================================================
// Prepass: x fp32 NCHW -> bf16 NHWC swizzled: xpre[b][row][col][ci^((col&7)<<3)]
// ===========================================================================
__global__ __launch_bounds__(256) void prepass_x(
    const float* __restrict__ x, unsigned short* __restrict__ xpre)
{
    __shared__ unsigned short ls[256 * 72];
    const int row = blockIdx.x, b = blockIdx.y;
    const int t = threadIdx.x;
    const int colq = t >> 2;
    const float* xb = x + ((size_t)(b * 64) * 256 + row) * 256;

    for (int sp = 0; sp < 4; ++sp) {
        const int cibase = sp * 16 + (t & 3) * 4;
        float4 v[4];
#pragma unroll
        for (int e = 0; e < 4; ++e)
            v[e] = *(const float4*)(xb + (size_t)(cibase + e) * 65536 + colq * 4);
#pragma unroll
        for (int jj = 0; jj < 4; ++jj) {
            const int col = colq * 4 + jj;
            const int sw  = (col & 7) << 3;
            ushort4 pk;
            pk.x = f2bf((&v[0].x)[jj]);
            pk.y = f2bf((&v[1].x)[jj]);
            pk.z = f2bf((&v[2].x)[jj]);
            pk.w = f2bf((&v[3].x)[jj]);
            *(ushort4*)&ls[col * 72 + (cibase ^ sw)] = pk;
        }
    }
    __syncthreads();
    unsigned short* xp = xpre + ((size_t)(b * 256 + row)) * 256 * 64;
    for (int q = 0; q < 8; ++q) {
        const int lin = q * 256 + t;
        const int col = lin >> 3, k = lin & 7;
        *(uint4*)(xp + col * 64 + k * 8) = *(const uint4*)&ls[col * 72 + k * 8];
    }
}

// ===========================================================================
// MFMA conv + fused masked group-stats partials (R11 v7, best measured).
// ===========================================================================
__global__ __launch_bounds__(512, 4) void conv_mfma(
    const unsigned short* __restrict__ xpre, const unsigned short* __restrict__ wpre,
    const float* __restrict__ bias, unsigned short* __restrict__ ybf,
    float* __restrict__ part)
{
    __shared__ unsigned short xs[10 * 40 * 64];   // 51200 B
    __shared__ unsigned short wl3[3][4096];       // 12288 B
    __shared__ float sred[8][16][2];              // 1024 B
    const int t = threadIdx.x, w = t >> 6, lane = t & 63;
    const int b = blockIdx.z, r0 = blockIdx.y * 8, c0 = blockIdx.x * 32;

    for (int L = w; L < 50; L += 8) {
        const int j = L / 5, i = L % 5;
        int rr = r0 - 1 + j; rr = rr < 0 ? 0 : (rr > 255 ? 255 : rr);
        int col = c0 - 2 + i * 8 + (lane >> 3);
        col = col < 0 ? 0 : (col > 255 ? 255 : col);
        const char* src = (const char*)xpre +
            ((size_t)((b * 256 + rr) * 256 + col)) * 128 + (lane & 7) * 16;
        gload_lds16(src, (char*)xs + j * 5120 + i * 1024);
    }
    gload_lds16((const char*)wpre + 0 * 8192 + w * 1024 + lane * 16,
                (char*)wl3[0] + w * 1024);
    gload_lds16((const char*)wpre + 1 * 8192 + w * 1024 + lane * 16,
                (char*)wl3[1] + w * 1024);

    const int l15 = lane & 15, lg = lane >> 4;
    const int sw15 = (l15 & 7) << 3;

    int jb[3];
#pragma unroll
    for (int kr = 0; kr < 3; ++kr) jb[kr] = (w + kr) * 5120;
    int offb[3][2][2];
#pragma unroll
    for (int kc = 0; kc < 3; ++kc)
#pragma unroll
        for (int n = 0; n < 2; ++n) {
            const int s = n * 16 + l15 + kc + 1;
#pragma unroll
            for (int ks = 0; ks < 2; ++ks) {
                const int cib = ks * 32 + lg * 8;
                offb[kc][n][ks] = s * 128 + ((cib ^ (((s + 6) & 7) << 3)) << 1);
            }
        }
    int afo[2][4];
#pragma unroll
    for (int ks = 0; ks < 2; ++ks)
#pragma unroll
        for (int m = 0; m < 4; ++m) {
            const int cib = ks * 32 + lg * 8;
            afo[ks][m] = (m * 16 + l15) * 128 + ((cib ^ sw15) << 1);
        }

    f32x4 acc[4][2];
#pragma unroll
    for (int m = 0; m < 4; ++m)
#pragma unroll
        for (int n = 0; n < 2; ++n)
            acc[m][n] = (f32x4){0.f, 0.f, 0.f, 0.f};

#pragma unroll
    for (int pos = 0; pos < 9; ++pos) {
        if (pos < 8) asm volatile("s_waitcnt vmcnt(1)" ::: "memory");
        else         asm volatile("s_waitcnt vmcnt(0)" ::: "memory");
        __builtin_amdgcn_s_barrier();
        __builtin_amdgcn_sched_barrier(0);
        if (pos + 2 <= 8)
            gload_lds16((const char*)wpre + (pos + 2) * 8192 + w * 1024 + lane * 16,
                        (char*)wl3[(pos + 2) % 3] + w * 1024);
        const int kr = pos / 3, kc = pos % 3;
        const char* wbuf = (const char*)wl3[pos % 3];
#pragma unroll
        for (int ks = 0; ks < 2; ++ks) {
            short8 bf[2], af[4];
#pragma unroll
            for (int n = 0; n < 2; ++n)
                bf[n] = *(const short8*)((const char*)xs + jb[kr] + offb[kc][n][ks]);
#pragma unroll
            for (int m = 0; m < 4; ++m)
                af[m] = *(const short8*)(wbuf + afo[ks][m]);
            __builtin_amdgcn_s_setprio(1);
#pragma unroll
            for (int m = 0; m < 4; ++m)
#pragma unroll
                for (int n = 0; n < 2; ++n)
                    acc[m][n] = __builtin_amdgcn_mfma_f32_16x16x32_bf16(
                        af[m], bf[n], acc[m][n], 0, 0, 0);
            __builtin_amdgcn_s_setprio(0);
        }
    }

    const int r = r0 + w;
    const bool rmask = (r != 0) && (r != 255);
    float s4[4] = {0.f, 0.f, 0.f, 0.f}, q4[4] = {0.f, 0.f, 0.f, 0.f};
#pragma unroll
    for (int m = 0; m < 4; ++m)
#pragma unroll
        for (int n = 0; n < 2; ++n) {
            const int c = c0 + n * 16 + l15;
            const bool pmask = rmask && (c != 0) && (c != 255);
#pragma unroll
            for (int reg = 0; reg < 4; ++reg) {
                const int co = m * 16 + lg * 4 + reg;
                const float v = acc[m][n][reg] + bias[co];
                ybf[(((size_t)b * 64 + co) * 256 + r) * 256 + c] = f2bf(v);
                if (pmask) { s4[m] += v; q4[m] += v * v; }
            }
        }
#pragma unroll
    for (int off = 1; off < 16; off <<= 1)
#pragma unroll
        for (int m = 0; m < 4; ++m) {
            s4[m] += __shfl_xor(s4[m], off);
            q4[m] += __shfl_xor(q4[m], off);
        }
    if (l15 == 0) {
#pragma unroll
        for (int m = 0; m < 4; ++m) {
            sred[w][m * 4 + lg][0] = s4[m];
            sred[w][m * 4 + lg][1] = q4[m];
        }
    }
    __syncthreads();
    if (t < 32) {
        const int g = t & 15, sel = t >> 4;
        float v = 0.f;
#pragma unroll
        for (int ww = 0; ww < 8; ++ww) v += sred[ww][g][sel];
        const int slot = blockIdx.y * 8 + blockIdx.x;      // 0..255
        part[((size_t)(b * 512 + slot) * 16 + g) * 2 + sel] = v;
    }
}

// ===========================================================================
// Edge interiors (no corners), 4 e-pixels per thread -> weight L2 traffic /4.
// grid (8 b, 4 edge, 16 seg); block 256 = 4 p-groups x 64 co; pe = p*4+e4.
// x patches staged to fp32 LDS once; weights read direct from L2 (coalesced,
// hoisted across the 4 e's). Stats partials -> slots 256..319.
// ===========================================================================
__global__ __launch_bounds__(256) void conv_edge3(
    const unsigned short* __restrict__ xpre, const float* __restrict__ wedge,
    const float* __restrict__ bias, unsigned short* __restrict__ ybf,
    float* __restrict__ part)
{
    __shared__ float xlf[16][9][64];   // 36864 B
    __shared__ float ered[4][16][2];   // 512 B
    const int b = blockIdx.x, edge = blockIdx.y, seg = blockIdx.z;
    const int t = threadIdx.x, p = t >> 6, lane = t & 63;

    // ---- stage x patches: 1152 units = 144 chunks (pe 0..15 x pos 0..8) x 8
    for (int unit = t; unit < 1152; unit += 256) {
        const int chunk = unit >> 3, sub = unit & 7;
        const int pe = chunk / 9, pos = chunk % 9;
        const int kr = pos / 3, kc = pos % 3;
        const int idx = seg * 16 + pe;
        int row, col;
        if (edge == 0)      { const int e = min(idx + 1, 254); row = 253 + kr; col = e - 1 + kc; }
        else if (edge == 1) { const int e = min(idx + 1, 254); row = kr;       col = e - 1 + kc; }
        else if (edge == 2) { const int e = min(idx, 253);     row = e + kr;   col = kc; }
        else                { const int e = min(idx, 253);     row = e + kr;   col = 253 + kc; }
        const uint4 v = *(const uint4*)(xpre +
            ((size_t)((b * 256 + row) * 256 + col)) * 64 + sub * 8);
        const int ci0 = (sub ^ (col & 7)) * 8;
        float* dst = &xlf[pe][pos][ci0];
        const unsigned short* hv = (const unsigned short*)&v;
#pragma unroll
        for (int j = 0; j < 8; ++j) dst[j] = bf2f(hv[j]);
    }
    __syncthreads();

    const int wid = 4 + edge;          // 4=bot 5=top 6=left 7=right
    const float* wbase = wedge + (size_t)wid * 36864;
    float acc4[4] = {0.f, 0.f, 0.f, 0.f};
#pragma unroll
    for (int pos = 0; pos < 9; ++pos) {
#pragma unroll
        for (int c4 = 0; c4 < 16; ++c4) {
            const float4 wv = *(const float4*)(wbase + pos * 4096 + c4 * 256 + lane * 4);
#pragma unroll
            for (int e4 = 0; e4 < 4; ++e4) {
                const float4 xv = *(const float4*)&xlf[p * 4 + e4][pos][c4 * 4];
                acc4[e4] = fmaf(wv.x, xv.x, acc4[e4]);
                acc4[e4] = fmaf(wv.y, xv.y, acc4[e4]);
                acc4[e4] = fmaf(wv.z, xv.z, acc4[e4]);
                acc4[e4] = fmaf(wv.w, xv.w, acc4[e4]);
            }
        }
    }

    const int co = lane;
    float s = 0.f, q = 0.f;
#pragma unroll
    for (int e4 = 0; e4 < 4; ++e4) {
        const int idx = seg * 16 + p * 4 + e4;
        bool active; int r_out, c_out;
        if (edge == 0)      { const int e = idx + 1; active = (e <= 254); r_out = 0;     c_out = e; }
        else if (edge == 1) { const int e = idx + 1; active = (e <= 254); r_out = 255;   c_out = e; }
        else if (edge == 2) { const int e = idx;     active = (e <= 253); r_out = e + 1; c_out = 0; }
        else                { const int e = idx;     active = (e <= 253); r_out = e + 1; c_out = 255; }
        const float v = acc4[e4] + bias[co];
        if (active) {
            ybf[(((size_t)b * 64 + co) * 256 + r_out) * 256 + c_out] = f2bf(v);
            s += v; q += v * v;
        }
    }
    s += __shfl_xor(s, 1); q += __shfl_xor(q, 1);
    s += __shfl_xor(s, 2); q += __shfl_xor(q, 2);
    if ((lane & 3) == 0) { ered[p][co >> 2][0] = s; ered[p][co >> 2][1] = q; }
    __syncthreads();
    if (t < 32) {
        const int g = t & 15, sel = t >> 4;
        const float r = ered[0][g][sel] + ered[1][g][sel] +
                        ered[2][g][sel] + ered[3][g][sel];
        const int slot = 256 + (edge * 16 + seg);          // 256..319
        part[((size_t)(b * 512 + slot) * 16 + g) * 2 + sel] = r;
    }
}

// ===========================================================================
// 4 corner pixels per batch + their stats partial (slot 320).
// grid (8 b); block 256 = 4 corners x 64 co.
// ===========================================================================
__global__ __launch_bounds__(256) void conv_corner2(
    const unsigned short* __restrict__ xpre, const float* __restrict__ wedge,
    const float* __restrict__ bias, unsigned short* __restrict__ ybf,
    float* __restrict__ part)
{
    __shared__ float cred[4][16][2];
    const int b = blockIdx.x, t = threadIdx.x;
    const int corner = t >> 6, co = t & 63;
    const int wid  = corner;                       // 0=bl 1=br 2=tl 3=tr
    const int row0 = (corner < 2) ? 253 : 0;
    const int col0 = (corner & 1) ? 253 : 0;
    const int r_out = (corner < 2) ? 0 : 255;
    const int c_out = (corner & 1) ? 255 : 0;

    const float* wbase = wedge + (size_t)wid * 36864;
    float acc = 0.f;
#pragma unroll
    for (int pos = 0; pos < 9; ++pos) {
        const int kr = pos / 3, kc = pos % 3;
        const int row = row0 + kr, col = col0 + kc;
        const unsigned short* xp = xpre + ((size_t)((b * 256 + row) * 256 + col)) * 64;
        const int sw = (col & 7) << 3;
        for (int ci = 0; ci < 64; ++ci) {
            const float wv = wbase[pos * 4096 + (ci >> 2) * 256 + co * 4 + (ci & 3)];
            const float xv = bf2f(xp[ci ^ sw]);
            acc = fmaf(wv, xv, acc);
        }
    }
    const float v = acc + bias[co];
    ybf[(((size_t)b * 64 + co) * 256 + r_out) * 256 + c_out] = f2bf(v);
    float s = v, q = v * v;
    s += __shfl_xor(s, 1); q += __shfl_xor(q, 1);
    s += __shfl_xor(s, 2); q += __shfl_xor(q, 2);
    if ((co & 3) == 0) { cred[corner][co >> 2][0] = s; cred[corner][co >> 2][1] = q; }
    __syncthreads();
    if (t < 32) {
        const int g = t & 15, sel = t >> 4;
        const float r = cred[0][g][sel] + cred[1][g][sel] +
                        cred[2][g][sel] + cred[3][g][sel];
        part[((size_t)(b * 512 + 320) * 16 + g) * 2 + sel] = r;
    }
}

// ===========================================================================
// Reduce 321 partial slots -> mean/rstd per (b, group).
// ===========================================================================
__global__ __launch_bounds__(256) void stats_reduce(
    const float* __restrict__ part, float* __restrict__ mv)
{
    __shared__ float sred[16][16][2];
    const int b = blockIdx.x, t = threadIdx.x;
    const int g = t & 15, chunk = t >> 4;
    float s = 0.f, q = 0.f;
    for (int k = 0; k < 21; ++k) {
        const int slot = chunk * 21 + k;
        if (slot < 321) {
            const size_t base = ((size_t)(b * 512 + slot) * 16 + g) * 2;
            s += part[base]; q += part[base + 1];
        }
    }
    sred[chunk][g][0] = s; sred[chunk][g][1] = q;
    __syncthreads();
    if (t < 16) {
        float S = 0.f, Q = 0.f;
#pragma unroll
        for (int c = 0; c < 16; ++c) { S += sred[c][t][0]; Q += sred[c][t][1]; }
        const float inv_n = 1.0f / (4.0f * 65536.0f);
        const float mean = S * inv_n;
        const float var  = Q * inv_n - mean * mean;
        mv[(b * 16 + t) * 2]     = mean;
        mv[(b * 16 + t) * 2 + 1] = rsqrtf(var + EPS_);
    }
}

// ===========================================================================
// GroupNorm + SELU: read bf16 ybf, write fp32 out. 8 elems/thread.
// ===========================================================================
__global__ __launch_bounds__(256) void norm_bf(
    const unsigned short* __restrict__ ybf, float* __restrict__ out,
    const float* __restrict__ mv,
    const float* __restrict__ gamma, const float* __restrict__ beta)
{
    const size_t tt = (size_t)blockIdx.x * 256 + threadIdx.x;
    const size_t e = tt * 8;
    const int b  = (int)(e >> 22);
    const int ch = (int)((e >> 16) & 63);
    const int g  = ch >> 2;
    const float mean = mv[(b * 16 + g) * 2];
    const float rstd = mv[(b * 16 + g) * 2 + 1];
    const float ga = gamma[ch] * rstd;
    const float be = beta[ch] - mean * ga;

    const uint4 v = *(const uint4*)(ybf + e);
    float f[8];
    f[0] = __uint_as_float(v.x << 16); f[1] = __uint_as_float(v.x & 0xffff0000u);
    f[2] = __uint_as_float(v.y << 16); f[3] = __uint_as_float(v.y & 0xffff0000u);
    f[4] = __uint_as_float(v.z << 16); f[5] = __uint_as_float(v.z & 0xffff0000u);
    f[6] = __uint_as_float(v.w << 16); f[7] = __uint_as_float(v.w & 0xffff0000u);
    float4 o0, o1;
    o0.x = selu_f(f[0] * ga + be); o0.y = selu_f(f[1] * ga + be);
    o0.z = selu_f(f[2] * ga + be); o0.w = selu_f(f[3] * ga + be);
    o1.x = selu_f(f[4] * ga + be); o1.y = selu_f(f[5] * ga + be);
    o1.z = selu_f(f[6] * ga + be); o1.w = selu_f(f[7] * ga + be);
    *(float4*)(out + e)     = o0;
    *(float4*)(out + e + 4) = o1;
}

// ===========================================================================
// Fallback path (round-1 proven kernels) for small ws.
// ===========================================================================
__global__ __launch_bounds__(256) void conv_main(
    const float* __restrict__ x, const float* __restrict__ w,
    const float* __restrict__ bias, float* __restrict__ y)
{
    const int c = threadIdx.x;
    const int r = blockIdx.x;
    const int b = blockIdx.y;
    const int rr = (r == 0) ? (H_ - 3) : ((r == H_ - 1) ? 0 : (r - 1));
    const int cc = min(max(c - 1, 0), W_ - 3);
    float acc[CO];
#pragma unroll
    for (int co = 0; co < CO; ++co) acc[co] = 0.f;
    const float* xb = x + (size_t)b * CI * H_ * W_;
    for (int ci = 0; ci < CI; ++ci) {
        const float* xp = xb + ((size_t)ci * H_ + rr) * W_ + cc;
        float xv[9];
#pragma unroll
        for (int kr = 0; kr < 3; ++kr)
#pragma unroll
            for (int kc = 0; kc < 3; ++kc)
                xv[kr * 3 + kc] = xp[kr * W_ + kc];
        const float* wci = w + ci * 9;
#pragma unroll
        for (int co = 0; co < CO; ++co) {
            const float* wp = wci + co * (CI * 9);
            float a = acc[co];
#pragma unroll
            for (int k = 0; k < 9; ++k) a = fmaf(xv[k], wp[k], a);
            acc[co] = a;
        }
    }
#pragma unroll
    for (int co = 0; co < CO; ++co)
        y[(((size_t)b * CO + co) * H_ + r) * W_ + c] = acc[co] + bias[co];
}

__global__ __launch_bounds__(256) void conv_edge(
    const float* __restrict__ x,
    const float* __restrict__ w_bot, const float* __restrict__ w_top,
    const float* __restrict__ w_left, const float* __restrict__ w_right,
    const float* __restrict__ bias, float* __restrict__ y)
{
    const int b     = blockIdx.x;
    const int edge  = blockIdx.y;
    const int seg   = blockIdx.z;
    const int el    = threadIdx.x & 63;
    const int chunk = threadIdx.x >> 6;
    const int e     = seg * 64 + el;
    const bool active = (e < 254);
    const int ec    = active ? e : 253;
    const float* w = (edge == 0) ? w_bot : (edge == 1) ? w_top
                   : (edge == 2) ? w_left : w_right;
    int r_out, c_out, rr, cc;
    if (edge == 0)      { r_out = 0;      c_out = 1 + ec; rr = H_ - 3; cc = ec; }
    else if (edge == 1) { r_out = H_ - 1; c_out = 1 + ec; rr = 0;      cc = ec; }
    else if (edge == 2) { r_out = 1 + ec; c_out = 0;      rr = ec;     cc = 0; }
    else                { r_out = 1 + ec; c_out = W_ - 1; rr = ec;     cc = W_ - 3; }
    float acc[CO];
#pragma unroll
    for (int co = 0; co < CO; ++co) acc[co] = 0.f;
    const float* xb = x + (size_t)b * CI * H_ * W_;
    const int ci0 = chunk * 16;
    for (int ci = ci0; ci < ci0 + 16; ++ci) {
        const float* xp = xb + ((size_t)ci * H_ + rr) * W_ + cc;
        float xv[9];
#pragma unroll
        for (int kr = 0; kr < 3; ++kr)
#pragma unroll
            for (int kc = 0; kc < 3; ++kc)
                xv[kr * 3 + kc] = xp[kr * W_ + kc];
#pragma unroll
        for (int co = 0; co < CO; ++co) {
            const float* wp = w + co * (CI * 9) + ci * 9;
            float a = acc[co];
#pragma unroll
            for (int k = 0; k < 9; ++k) a = fmaf(xv[k], wp[k], a);
            acc[co] = a;
        }
    }
    __shared__ float lds[64][65];
    for (int s = 0; s < 4; ++s) {
        if (chunk == s) {
            if (s == 0) {
#pragma unroll
                for (int co = 0; co < CO; ++co) lds[el][co] = acc[co];
            } else {
#pragma unroll
                for (int co = 0; co < CO; ++co) lds[el][co] += acc[co];
            }
        }
        __syncthreads();
    }
    if (chunk == 0 && active) {
#pragma unroll
        for (int co = 0; co < CO; ++co)
            y[(((size_t)b * CO + co) * H_ + r_out) * W_ + c_out] = lds[el][co] + bias[co];
    }
}

__global__ __launch_bounds__(256) void conv_corner(
    const float* __restrict__ x,
    const float* __restrict__ w_bl, const float* __restrict__ w_br,
    const float* __restrict__ w_tl, const float* __restrict__ w_tr,
    const float* __restrict__ bias, float* __restrict__ y)
{
    const int b      = blockIdx.x;
    const int corner = threadIdx.x >> 6;
    const int co     = threadIdx.x & 63;
    const float* w = (corner == 0) ? w_bl : (corner == 1) ? w_br
                   : (corner == 2) ? w_tl : w_tr;
    const int rr    = (corner < 2) ? (H_ - 3) : 0;
    const int cc    = (corner & 1) ? (W_ - 3) : 0;
    const int r_out = (corner < 2) ? 0 : (H_ - 1);
    const int c_out = (corner & 1) ? (W_ - 1) : 0;
    const float* xb = x + (size_t)b * CI * H_ * W_;
    float a = 0.f;
    for (int ci = 0; ci < CI; ++ci) {
        const float* xp = xb + ((size_t)ci * H_ + rr) * W_ + cc;
        const float* wp = w + ((size_t)co * CI + ci) * 9;
#pragma unroll
        for (int kr = 0; kr < 3; ++kr)
#pragma unroll
            for (int kc = 0; kc < 3; ++kc)
                a = fmaf(xp[kr * W_ + kc], wp[kr * 3 + kc], a);
    }
    y[(((size_t)b * CO + co) * H_ + r_out) * W_ + c_out] = a + bias[co];
}

__global__ __launch_bounds__(256) void stats_kernel(
    const float* __restrict__ y, float* __restrict__ ws)
{
    const int bid   = blockIdx.x;
    const int chunk = bid & 3;
    const int g     = (bid >> 2) & 15;
    const int b     = bid >> 6;
    const float* p  = y + ((size_t)(b * 64 + g * 4 + chunk)) * (H_ * W_);
    float s = 0.f, q = 0.f;
    for (int i = threadIdx.x; i < (H_ * W_ / 4); i += 256) {
        float4 v = reinterpret_cast<const float4*>(p)[i];
        s += v.x + v.y + v.z + v.w;
        q += v.x * v.x + v.y * v.y + v.z * v.z + v.w * v.w;
    }
#pragma unroll
    for (int off = 32; off; off >>= 1) {
        s += __shfl_down(s, off);
        q += __shfl_down(q, off);
    }
    __shared__ float red[8];
    const int wid = threadIdx.x >> 6;
    if ((threadIdx.x & 63) == 0) { red[wid * 2] = s; red[wid * 2 + 1] = q; }
    __syncthreads();
    if (threadIdx.x == 0) {
        ws[bid * 2]     = red[0] + red[2] + red[4] + red[6];
        ws[bid * 2 + 1] = red[1] + red[3] + red[5] + red[7];
    }
}

__global__ __launch_bounds__(256) void norm_stats(
    float* __restrict__ y, const float* __restrict__ st,
    const float* __restrict__ gamma, const float* __restrict__ beta)
{
    const size_t t = (size_t)blockIdx.x * 256 + threadIdx.x;
    const size_t e = t * 4;
    const int b  = (int)(e >> 22);
    const int ch = (int)((e >> 16) & 63);
    const int g  = ch >> 2;
    const int sb = ((b * 16 + g) * 4) * 2;
    const float S = st[sb] + st[sb + 2] + st[sb + 4] + st[sb + 6];
    const float Q = st[sb + 1] + st[sb + 3] + st[sb + 5] + st[sb + 7];
    const float inv_n = 1.0f / (4.0f * H_ * W_);
    const float mean  = S * inv_n;
    const float var   = Q * inv_n - mean * mean;
    const float rstd  = rsqrtf(var + EPS_);
    const float ga = gamma[ch] * rstd;
    const float be = beta[ch] - mean * ga;
    float4 v = reinterpret_cast<float4*>(y)[t];
    float u;
    u = v.x * ga + be; v.x = selu_f(u);
    u = v.y * ga + be; v.y = selu_f(u);
    u = v.z * ga + be; v.z = selu_f(u);
    u = v.w * ga + be; v.w = selu_f(u);
    reinterpret_cast<float4*>(y)[t] = v;
}

extern "C" void kernel_launch(void* const* d_in, const int* in_sizes, int n_in,
                              void* d_out, int out_size, void* d_ws, size_t ws_size,
                              hipStream_t stream) {
    const float* x       = (const float*)d_in[0];
    const float* w_int   = (const float*)d_in[1];
    const float* w_tl    = (const float*)d_in[2];
    const float* w_tr    = (const float*)d_in[3];
    const float* w_bl    = (const float*)d_in[4];
    const float* w_br    = (const float*)d_in[5];
    const float* w_top   = (const float*)d_in[6];
    const float* w_bot   = (const float*)d_in[7];
    const float* w_left  = (const float*)d_in[8];
    const float* w_right = (const float*)d_in[9];
    const float* bias    = (const float*)d_in[10];
    const float* gamma   = (const float*)d_in[11];
    const float* beta    = (const float*)d_in[12];

    float* out = (float*)d_out;

    const size_t XPRE  = 67108864ull;                  // bf16 x NHWC
    const size_t YBF   = 67108864ull;                  // bf16 y NCHW
    const size_t WPRE  = 73728ull;                     // bf16 w_int
    const size_t WEDGE = 1179648ull;                   // fp32 [8][9][16][64][4]
    const size_t PART  = 524288ull;                    // [8][512][16][2] f32
    const size_t MV    = 1024ull;                      // [8][16][2] f32
    const size_t NEED  = XPRE + YBF + WPRE + WEDGE + PART + MV;

    if (ws_size >= NEED) {
        unsigned short* xpre = (unsigned short*)d_ws;
        unsigned short* ybf  = (unsigned short*)((char*)d_ws + XPRE);
        unsigned short* wpre = (unsigned short*)((char*)d_ws + XPRE + YBF);
        float* wedge = (float*)((char*)d_ws + XPRE + YBF + WPRE);
        float* part  = (float*)((char*)d_ws + XPRE + YBF + WPRE + WEDGE);
        float* mv    = (float*)((char*)d_ws + XPRE + YBF + WPRE + WEDGE + PART);

        prepass_weights<<<dim3(81), 256, 0, stream>>>(
            w_int, w_bl, w_br, w_tl, w_tr, w_bot, w_top, w_left, w_right, wpre, wedge);
        prepass_x<<<dim3(256, 8), 256, 0, stream>>>(x, xpre);
        conv_mfma<<<dim3(8, 32, 8), 512, 0, stream>>>(xpre, wpre, bias, ybf, part);
        conv_edge3<<<dim3(8, 4, 16), 256, 0, stream>>>(xpre, wedge, bias, ybf, part);
        conv_corner2<<<dim3(8), 256, 0, stream>>>(xpre, wedge, bias, ybf, part);
        stats_reduce<<<dim3(8), 256, 0, stream>>>(part, mv);
        norm_bf<<<dim3(16384), 256, 0, stream>>>(ybf, out, mv, gamma, beta);
    } else {
        float* stats = (float*)d_ws;
        conv_main<<<dim3(H_, B_), 256, 0, stream>>>(x, w_int, bias, out);
        conv_edge<<<dim3(B_, 4, 4), 256, 0, stream>>>(x, w_bot, w_top, w_left, w_right, bias, out);
        conv_corner<<<dim3(B_), 256, 0, stream>>>(x, w_bl, w_br, w_tl, w_tr, bias, out);
        stats_kernel<<<dim3(512), 256, 0, stream>>>(out, stats);
        norm_stats<<<dim3(32768), 256, 0, stream>>>(out, stats, gamma, beta);
    }
}

// Round 14
// 226.750 us; speedup vs baseline: 5.0574x; 5.0574x over previous
//
#include <hip/hip_runtime.h>

#define B_ 8
#define CI 64
#define CO 64
#define H_ 256
#define W_ 256
#define EPS_ 1e-5f

#define SELU_SCALE 1.0507009873554805f
#define SELU_SA    1.7580993408473766f

typedef __attribute__((ext_vector_type(8))) short short8;
typedef __attribute__((ext_vector_type(4))) float f32x4;
typedef unsigned int u32;

__device__ __forceinline__ unsigned short f2bf(float f) {
    unsigned int u = __float_as_uint(f);
    u = (u + 0x7fffu + ((u >> 16) & 1u)) >> 16;
    return (unsigned short)u;
}
__device__ __forceinline__ float bf2f(unsigned short h) {
    return __uint_as_float(((unsigned)h) << 16);
}
__device__ __forceinline__ float selu_f(float u) {
    return (u > 0.f) ? SELU_SCALE * u : SELU_SA * (__expf(u) - 1.f);
}
__device__ __forceinline__ void gload_lds16(const void* g, void* l) {
    __builtin_amdgcn_global_load_lds(
        (const __attribute__((address_space(1))) u32*)g,
        (__attribute__((address_space(3))) u32*)l, 16, 0, 0);
}

// ===========================================================================
// Weight prepass.
// blocks 0..71: wedge[wid][pos][ci4][co][j] fp32 AND wedgebf (bf16 copy).
//               (0=bl 1=br 2=tl 3=tr 4=bot 5=top 6=left 7=right)
// blocks 72..80: wpre[pos][co][ci ^ ((co&7)<<3)] bf16 from w_int
// ===========================================================================
__global__ __launch_bounds__(256) void prepass_weights(
    const float* __restrict__ w_int,
    const float* __restrict__ w_bl, const float* __restrict__ w_br,
    const float* __restrict__ w_tl, const float* __restrict__ w_tr,
    const float* __restrict__ w_bot, const float* __restrict__ w_top,
    const float* __restrict__ w_left, const float* __restrict__ w_right,
    unsigned short* __restrict__ wpre, float* __restrict__ wedge,
    unsigned short* __restrict__ wedgebf)
{
    const int blk = blockIdx.x, t = threadIdx.x;
    if (blk < 72) {
        const int wid = blk / 9, pos = blk % 9;
        const float* src = (wid == 0) ? w_bl : (wid == 1) ? w_br
                         : (wid == 2) ? w_tl : (wid == 3) ? w_tr
                         : (wid == 4) ? w_bot : (wid == 5) ? w_top
                         : (wid == 6) ? w_left : w_right;
        float* dst = wedge + (size_t)blk * 4096;
        unsigned short* dstbf = wedgebf + (size_t)blk * 4096;
        for (int k = 0; k < 16; ++k) {
            const int lin = k * 256 + t;        // [ci4][co][j]
            const int c4  = lin >> 8;
            const int co  = (lin >> 2) & 63;
            const int j   = lin & 3;
            const int ci  = c4 * 4 + j;
            const float v = src[(co * 64 + ci) * 9 + pos];
            dst[lin] = v;
            dstbf[lin] = f2bf(v);
        }
    } else {
        const int pos = blk - 72;
        for (int k = 0; k < 16; ++k) {
            const int lin = k * 256 + t;
            const int co = lin >> 6, cip = lin & 63;
            const int ci = cip ^ ((co & 7) << 3);
            wpre[pos * 4096 + lin] = f2bf(w_int[(co * 64 + ci) * 9 + pos]);
        }
    }
}

// ===========================================================================
// Prepass: x fp32 NCHW -> bf16 NHWC swizzled: xpre[b][row][col][ci^((col&7)<<3)]
// ===========================================================================
__global__ __launch_bounds__(256) void prepass_x(
    const float* __restrict__ x, unsigned short* __restrict__ xpre)
{
    __shared__ unsigned short ls[256 * 72];
    const int row = blockIdx.x, b = blockIdx.y;
    const int t = threadIdx.x;
    const int colq = t >> 2;
    const float* xb = x + ((size_t)(b * 64) * 256 + row) * 256;

    for (int sp = 0; sp < 4; ++sp) {
        const int cibase = sp * 16 + (t & 3) * 4;
        float4 v[4];
#pragma unroll
        for (int e = 0; e < 4; ++e)
            v[e] = *(const float4*)(xb + (size_t)(cibase + e) * 65536 + colq * 4);
#pragma unroll
        for (int jj = 0; jj < 4; ++jj) {
            const int col = colq * 4 + jj;
            const int sw  = (col & 7) << 3;
            ushort4 pk;
            pk.x = f2bf((&v[0].x)[jj]);
            pk.y = f2bf((&v[1].x)[jj]);
            pk.z = f2bf((&v[2].x)[jj]);
            pk.w = f2bf((&v[3].x)[jj]);
            *(ushort4*)&ls[col * 72 + (cibase ^ sw)] = pk;
        }
    }
    __syncthreads();
    unsigned short* xp = xpre + ((size_t)(b * 256 + row)) * 256 * 64;
    for (int q = 0; q < 8; ++q) {
        const int lin = q * 256 + t;
        const int col = lin >> 3, k = lin & 7;
        *(uint4*)(xp + col * 64 + k * 8) = *(const uint4*)&ls[col * 72 + k * 8];
    }
}

// ===========================================================================
// MFMA conv + fused masked group-stats partials (R11 v7, best measured).
// ===========================================================================
__global__ __launch_bounds__(512, 4) void conv_mfma(
    const unsigned short* __restrict__ xpre, const unsigned short* __restrict__ wpre,
    const float* __restrict__ bias, unsigned short* __restrict__ ybf,
    float* __restrict__ part)
{
    __shared__ unsigned short xs[10 * 40 * 64];   // 51200 B
    __shared__ unsigned short wl3[3][4096];       // 12288 B
    __shared__ float sred[8][16][2];              // 1024 B
    const int t = threadIdx.x, w = t >> 6, lane = t & 63;
    const int b = blockIdx.z, r0 = blockIdx.y * 8, c0 = blockIdx.x * 32;

    for (int L = w; L < 50; L += 8) {
        const int j = L / 5, i = L % 5;
        int rr = r0 - 1 + j; rr = rr < 0 ? 0 : (rr > 255 ? 255 : rr);
        int col = c0 - 2 + i * 8 + (lane >> 3);
        col = col < 0 ? 0 : (col > 255 ? 255 : col);
        const char* src = (const char*)xpre +
            ((size_t)((b * 256 + rr) * 256 + col)) * 128 + (lane & 7) * 16;
        gload_lds16(src, (char*)xs + j * 5120 + i * 1024);
    }
    gload_lds16((const char*)wpre + 0 * 8192 + w * 1024 + lane * 16,
                (char*)wl3[0] + w * 1024);
    gload_lds16((const char*)wpre + 1 * 8192 + w * 1024 + lane * 16,
                (char*)wl3[1] + w * 1024);

    const int l15 = lane & 15, lg = lane >> 4;
    const int sw15 = (l15 & 7) << 3;

    int jb[3];
#pragma unroll
    for (int kr = 0; kr < 3; ++kr) jb[kr] = (w + kr) * 5120;
    int offb[3][2][2];
#pragma unroll
    for (int kc = 0; kc < 3; ++kc)
#pragma unroll
        for (int n = 0; n < 2; ++n) {
            const int s = n * 16 + l15 + kc + 1;
#pragma unroll
            for (int ks = 0; ks < 2; ++ks) {
                const int cib = ks * 32 + lg * 8;
                offb[kc][n][ks] = s * 128 + ((cib ^ (((s + 6) & 7) << 3)) << 1);
            }
        }
    int afo[2][4];
#pragma unroll
    for (int ks = 0; ks < 2; ++ks)
#pragma unroll
        for (int m = 0; m < 4; ++m) {
            const int cib = ks * 32 + lg * 8;
            afo[ks][m] = (m * 16 + l15) * 128 + ((cib ^ sw15) << 1);
        }

    f32x4 acc[4][2];
#pragma unroll
    for (int m = 0; m < 4; ++m)
#pragma unroll
        for (int n = 0; n < 2; ++n)
            acc[m][n] = (f32x4){0.f, 0.f, 0.f, 0.f};

#pragma unroll
    for (int pos = 0; pos < 9; ++pos) {
        if (pos < 8) asm volatile("s_waitcnt vmcnt(1)" ::: "memory");
        else         asm volatile("s_waitcnt vmcnt(0)" ::: "memory");
        __builtin_amdgcn_s_barrier();
        __builtin_amdgcn_sched_barrier(0);
        if (pos + 2 <= 8)
            gload_lds16((const char*)wpre + (pos + 2) * 8192 + w * 1024 + lane * 16,
                        (char*)wl3[(pos + 2) % 3] + w * 1024);
        const int kr = pos / 3, kc = pos % 3;
        const char* wbuf = (const char*)wl3[pos % 3];
#pragma unroll
        for (int ks = 0; ks < 2; ++ks) {
            short8 bf[2], af[4];
#pragma unroll
            for (int n = 0; n < 2; ++n)
                bf[n] = *(const short8*)((const char*)xs + jb[kr] + offb[kc][n][ks]);
#pragma unroll
            for (int m = 0; m < 4; ++m)
                af[m] = *(const short8*)(wbuf + afo[ks][m]);
            __builtin_amdgcn_s_setprio(1);
#pragma unroll
            for (int m = 0; m < 4; ++m)
#pragma unroll
                for (int n = 0; n < 2; ++n)
                    acc[m][n] = __builtin_amdgcn_mfma_f32_16x16x32_bf16(
                        af[m], bf[n], acc[m][n], 0, 0, 0);
            __builtin_amdgcn_s_setprio(0);
        }
    }

    const int r = r0 + w;
    const bool rmask = (r != 0) && (r != 255);
    float s4[4] = {0.f, 0.f, 0.f, 0.f}, q4[4] = {0.f, 0.f, 0.f, 0.f};
#pragma unroll
    for (int m = 0; m < 4; ++m)
#pragma unroll
        for (int n = 0; n < 2; ++n) {
            const int c = c0 + n * 16 + l15;
            const bool pmask = rmask && (c != 0) && (c != 255);
#pragma unroll
            for (int reg = 0; reg < 4; ++reg) {
                const int co = m * 16 + lg * 4 + reg;
                const float v = acc[m][n][reg] + bias[co];
                ybf[(((size_t)b * 64 + co) * 256 + r) * 256 + c] = f2bf(v);
                if (pmask) { s4[m] += v; q4[m] += v * v; }
            }
        }
#pragma unroll
    for (int off = 1; off < 16; off <<= 1)
#pragma unroll
        for (int m = 0; m < 4; ++m) {
            s4[m] += __shfl_xor(s4[m], off);
            q4[m] += __shfl_xor(q4[m], off);
        }
    if (l15 == 0) {
#pragma unroll
        for (int m = 0; m < 4; ++m) {
            sred[w][m * 4 + lg][0] = s4[m];
            sred[w][m * 4 + lg][1] = q4[m];
        }
    }
    __syncthreads();
    if (t < 32) {
        const int g = t & 15, sel = t >> 4;
        float v = 0.f;
#pragma unroll
        for (int ww = 0; ww < 8; ++ww) v += sred[ww][g][sel];
        const int slot = blockIdx.y * 8 + blockIdx.x;      // 0..255
        part[((size_t)(b * 512 + slot) * 16 + g) * 2 + sel] = v;
    }
}

// ===========================================================================
// Edge interiors, 4 px/thread, ALL-LDS compute (no spill, no L2 streaming):
// weights staged per block as bf16 (73.7 KB via gload_lds), x as fp32 LDS.
// grid (8 b, 4 edge, 16 seg); block 256 = 4 p x 64 co. Slots 256..319.
// ===========================================================================
__global__ __launch_bounds__(256) void conv_edge4(
    const unsigned short* __restrict__ xpre, const unsigned short* __restrict__ wedgebf,
    const float* __restrict__ bias, unsigned short* __restrict__ ybf,
    float* __restrict__ part)
{
    __shared__ unsigned short wsl[9 * 4096];  // 73728 B
    __shared__ float xlf[16][9][64];          // 36864 B
    __shared__ float ered[4][16][2];          // 512 B
    const int b = blockIdx.x, edge = blockIdx.y, seg = blockIdx.z;
    const int t = threadIdx.x, p = t >> 6, lane = t & 63;
    const int wid = 4 + edge;                 // 4=bot 5=top 6=left 7=right

    // ---- stage weights: 72 KB linear, 18 chunks per wave (async)
    const char* wsrc = (const char*)wedgebf + (size_t)wid * 73728;
    for (int L = p * 18; L < p * 18 + 18; ++L)
        gload_lds16(wsrc + L * 1024 + lane * 16, (char*)wsl + L * 1024);

    // ---- stage x patches: 1152 units = 144 chunks (pe x pos) x 8 subs
    for (int unit = t; unit < 1152; unit += 256) {
        const int chunk = unit >> 3, sub = unit & 7;
        const int pe = chunk / 9, pos = chunk % 9;
        const int kr = pos / 3, kc = pos % 3;
        const int idx = seg * 16 + pe;
        int row, col;
        if (edge == 0)      { const int e = min(idx + 1, 254); row = 253 + kr; col = e - 1 + kc; }
        else if (edge == 1) { const int e = min(idx + 1, 254); row = kr;       col = e - 1 + kc; }
        else if (edge == 2) { const int e = min(idx, 253);     row = e + kr;   col = kc; }
        else                { const int e = min(idx, 253);     row = e + kr;   col = 253 + kc; }
        const uint4 v = *(const uint4*)(xpre +
            ((size_t)((b * 256 + row) * 256 + col)) * 64 + sub * 8);
        const int ci0 = (sub ^ (col & 7)) * 8;
        float* dst = &xlf[pe][pos][ci0];
        const unsigned short* hv = (const unsigned short*)&v;
#pragma unroll
        for (int j = 0; j < 8; ++j) dst[j] = bf2f(hv[j]);
    }
    __syncthreads();   // drains vmcnt (gload_lds) + lgkm

    float acc4[4] = {0.f, 0.f, 0.f, 0.f};
#pragma unroll 1
    for (int pos = 0; pos < 9; ++pos) {
#pragma unroll
        for (int c4 = 0; c4 < 16; ++c4) {
            const ushort4 wv4 = *(const ushort4*)&wsl[pos * 4096 + c4 * 256 + lane * 4];
            const float w0 = bf2f(wv4.x), w1 = bf2f(wv4.y);
            const float w2 = bf2f(wv4.z), w3 = bf2f(wv4.w);
#pragma unroll
            for (int e4 = 0; e4 < 4; ++e4) {
                const float4 xv = *(const float4*)&xlf[p * 4 + e4][pos][c4 * 4];
                acc4[e4] = fmaf(w0, xv.x, acc4[e4]);
                acc4[e4] = fmaf(w1, xv.y, acc4[e4]);
                acc4[e4] = fmaf(w2, xv.z, acc4[e4]);
                acc4[e4] = fmaf(w3, xv.w, acc4[e4]);
            }
        }
    }

    const int co = lane;
    float s = 0.f, q = 0.f;
#pragma unroll
    for (int e4 = 0; e4 < 4; ++e4) {
        const int idx = seg * 16 + p * 4 + e4;
        bool active; int r_out, c_out;
        if (edge == 0)      { const int e = idx + 1; active = (e <= 254); r_out = 0;     c_out = e; }
        else if (edge == 1) { const int e = idx + 1; active = (e <= 254); r_out = 255;   c_out = e; }
        else if (edge == 2) { const int e = idx;     active = (e <= 253); r_out = e + 1; c_out = 0; }
        else                { const int e = idx;     active = (e <= 253); r_out = e + 1; c_out = 255; }
        const float v = acc4[e4] + bias[co];
        if (active) {
            ybf[(((size_t)b * 64 + co) * 256 + r_out) * 256 + c_out] = f2bf(v);
            s += v; q += v * v;
        }
    }
    s += __shfl_xor(s, 1); q += __shfl_xor(q, 1);
    s += __shfl_xor(s, 2); q += __shfl_xor(q, 2);
    if ((lane & 3) == 0) { ered[p][co >> 2][0] = s; ered[p][co >> 2][1] = q; }
    __syncthreads();
    if (t < 32) {
        const int g = t & 15, sel = t >> 4;
        const float r = ered[0][g][sel] + ered[1][g][sel] +
                        ered[2][g][sel] + ered[3][g][sel];
        const int slot = 256 + (edge * 16 + seg);          // 256..319
        part[((size_t)(b * 512 + slot) * 16 + g) * 2 + sel] = r;
    }
}

// ===========================================================================
// 4 corner pixels per batch + their stats partial (slot 320).
// ===========================================================================
__global__ __launch_bounds__(256) void conv_corner2(
    const unsigned short* __restrict__ xpre, const float* __restrict__ wedge,
    const float* __restrict__ bias, unsigned short* __restrict__ ybf,
    float* __restrict__ part)
{
    __shared__ float cred[4][16][2];
    const int b = blockIdx.x, t = threadIdx.x;
    const int corner = t >> 6, co = t & 63;
    const int wid  = corner;                       // 0=bl 1=br 2=tl 3=tr
    const int row0 = (corner < 2) ? 253 : 0;
    const int col0 = (corner & 1) ? 253 : 0;
    const int r_out = (corner < 2) ? 0 : 255;
    const int c_out = (corner & 1) ? 255 : 0;

    const float* wbase = wedge + (size_t)wid * 36864;
    float acc = 0.f;
#pragma unroll
    for (int pos = 0; pos < 9; ++pos) {
        const int kr = pos / 3, kc = pos % 3;
        const int row = row0 + kr, col = col0 + kc;
        const unsigned short* xp = xpre + ((size_t)((b * 256 + row) * 256 + col)) * 64;
        const int sw = (col & 7) << 3;
        for (int ci = 0; ci < 64; ++ci) {
            const float wv = wbase[pos * 4096 + (ci >> 2) * 256 + co * 4 + (ci & 3)];
            const float xv = bf2f(xp[ci ^ sw]);
            acc = fmaf(wv, xv, acc);
        }
    }
    const float v = acc + bias[co];
    ybf[(((size_t)b * 64 + co) * 256 + r_out) * 256 + c_out] = f2bf(v);
    float s = v, q = v * v;
    s += __shfl_xor(s, 1); q += __shfl_xor(q, 1);
    s += __shfl_xor(s, 2); q += __shfl_xor(q, 2);
    if ((co & 3) == 0) { cred[corner][co >> 2][0] = s; cred[corner][co >> 2][1] = q; }
    __syncthreads();
    if (t < 32) {
        const int g = t & 15, sel = t >> 4;
        const float r = cred[0][g][sel] + cred[1][g][sel] +
                        cred[2][g][sel] + cred[3][g][sel];
        part[((size_t)(b * 512 + 320) * 16 + g) * 2 + sel] = r;
    }
}

// ===========================================================================
// Reduce 321 partial slots -> mean/rstd per (b, group).
// ===========================================================================
__global__ __launch_bounds__(256) void stats_reduce(
    const float* __restrict__ part, float* __restrict__ mv)
{
    __shared__ float sred[16][16][2];
    const int b = blockIdx.x, t = threadIdx.x;
    const int g = t & 15, chunk = t >> 4;
    float s = 0.f, q = 0.f;
    for (int k = 0; k < 21; ++k) {
        const int slot = chunk * 21 + k;
        if (slot < 321) {
            const size_t base = ((size_t)(b * 512 + slot) * 16 + g) * 2;
            s += part[base]; q += part[base + 1];
        }
    }
    sred[chunk][g][0] = s; sred[chunk][g][1] = q;
    __syncthreads();
    if (t < 16) {
        float S = 0.f, Q = 0.f;
#pragma unroll
        for (int c = 0; c < 16; ++c) { S += sred[c][t][0]; Q += sred[c][t][1]; }
        const float inv_n = 1.0f / (4.0f * 65536.0f);
        const float mean = S * inv_n;
        const float var  = Q * inv_n - mean * mean;
        mv[(b * 16 + t) * 2]     = mean;
        mv[(b * 16 + t) * 2 + 1] = rsqrtf(var + EPS_);
    }
}

// ===========================================================================
// GroupNorm + SELU: read bf16 ybf, write fp32 out. 8 elems/thread.
// ===========================================================================
__global__ __launch_bounds__(256) void norm_bf(
    const unsigned short* __restrict__ ybf, float* __restrict__ out,
    const float* __restrict__ mv,
    const float* __restrict__ gamma, const float* __restrict__ beta)
{
    const size_t tt = (size_t)blockIdx.x * 256 + threadIdx.x;
    const size_t e = tt * 8;
    const int b  = (int)(e >> 22);
    const int ch = (int)((e >> 16) & 63);
    const int g  = ch >> 2;
    const float mean = mv[(b * 16 + g) * 2];
    const float rstd = mv[(b * 16 + g) * 2 + 1];
    const float ga = gamma[ch] * rstd;
    const float be = beta[ch] - mean * ga;

    const uint4 v = *(const uint4*)(ybf + e);
    float f[8];
    f[0] = __uint_as_float(v.x << 16); f[1] = __uint_as_float(v.x & 0xffff0000u);
    f[2] = __uint_as_float(v.y << 16); f[3] = __uint_as_float(v.y & 0xffff0000u);
    f[4] = __uint_as_float(v.z << 16); f[5] = __uint_as_float(v.z & 0xffff0000u);
    f[6] = __uint_as_float(v.w << 16); f[7] = __uint_as_float(v.w & 0xffff0000u);
    float4 o0, o1;
    o0.x = selu_f(f[0] * ga + be); o0.y = selu_f(f[1] * ga + be);
    o0.z = selu_f(f[2] * ga + be); o0.w = selu_f(f[3] * ga + be);
    o1.x = selu_f(f[4] * ga + be); o1.y = selu_f(f[5] * ga + be);
    o1.z = selu_f(f[6] * ga + be); o1.w = selu_f(f[7] * ga + be);
    *(float4*)(out + e)     = o0;
    *(float4*)(out + e + 4) = o1;
}

// ===========================================================================
// Fallback path (round-1 proven kernels) for small ws.
// ===========================================================================
__global__ __launch_bounds__(256) void conv_main(
    const float* __restrict__ x, const float* __restrict__ w,
    const float* __restrict__ bias, float* __restrict__ y)
{
    const int c = threadIdx.x;
    const int r = blockIdx.x;
    const int b = blockIdx.y;
    const int rr = (r == 0) ? (H_ - 3) : ((r == H_ - 1) ? 0 : (r - 1));
    const int cc = min(max(c - 1, 0), W_ - 3);
    float acc[CO];
#pragma unroll
    for (int co = 0; co < CO; ++co) acc[co] = 0.f;
    const float* xb = x + (size_t)b * CI * H_ * W_;
    for (int ci = 0; ci < CI; ++ci) {
        const float* xp = xb + ((size_t)ci * H_ + rr) * W_ + cc;
        float xv[9];
#pragma unroll
        for (int kr = 0; kr < 3; ++kr)
#pragma unroll
            for (int kc = 0; kc < 3; ++kc)
                xv[kr * 3 + kc] = xp[kr * W_ + kc];
        const float* wci = w + ci * 9;
#pragma unroll
        for (int co = 0; co < CO; ++co) {
            const float* wp = wci + co * (CI * 9);
            float a = acc[co];
#pragma unroll
            for (int k = 0; k < 9; ++k) a = fmaf(xv[k], wp[k], a);
            acc[co] = a;
        }
    }
#pragma unroll
    for (int co = 0; co < CO; ++co)
        y[(((size_t)b * CO + co) * H_ + r) * W_ + c] = acc[co] + bias[co];
}

__global__ __launch_bounds__(256) void conv_edge(
    const float* __restrict__ x,
    const float* __restrict__ w_bot, const float* __restrict__ w_top,
    const float* __restrict__ w_left, const float* __restrict__ w_right,
    const float* __restrict__ bias, float* __restrict__ y)
{
    const int b     = blockIdx.x;
    const int edge  = blockIdx.y;
    const int seg   = blockIdx.z;
    const int el    = threadIdx.x & 63;
    const int chunk = threadIdx.x >> 6;
    const int e     = seg * 64 + el;
    const bool active = (e < 254);
    const int ec    = active ? e : 253;
    const float* w = (edge == 0) ? w_bot : (edge == 1) ? w_top
                   : (edge == 2) ? w_left : w_right;
    int r_out, c_out, rr, cc;
    if (edge == 0)      { r_out = 0;      c_out = 1 + ec; rr = H_ - 3; cc = ec; }
    else if (edge == 1) { r_out = H_ - 1; c_out = 1 + ec; rr = 0;      cc = ec; }
    else if (edge == 2) { r_out = 1 + ec; c_out = 0;      rr = ec;     cc = 0; }
    else                { r_out = 1 + ec; c_out = W_ - 1; rr = ec;     cc = W_ - 3; }
    float acc[CO];
#pragma unroll
    for (int co = 0; co < CO; ++co) acc[co] = 0.f;
    const float* xb = x + (size_t)b * CI * H_ * W_;
    const int ci0 = chunk * 16;
    for (int ci = ci0; ci < ci0 + 16; ++ci) {
        const float* xp = xb + ((size_t)ci * H_ + rr) * W_ + cc;
        float xv[9];
#pragma unroll
        for (int kr = 0; kr < 3; ++kr)
#pragma unroll
            for (int kc = 0; kc < 3; ++kc)
                xv[kr * 3 + kc] = xp[kr * W_ + kc];
#pragma unroll
        for (int co = 0; co < CO; ++co) {
            const float* wp = w + co * (CI * 9) + ci * 9;
            float a = acc[co];
#pragma unroll
            for (int k = 0; k < 9; ++k) a = fmaf(xv[k], wp[k], a);
            acc[co] = a;
        }
    }
    __shared__ float lds[64][65];
    for (int s = 0; s < 4; ++s) {
        if (chunk == s) {
            if (s == 0) {
#pragma unroll
                for (int co = 0; co < CO; ++co) lds[el][co] = acc[co];
            } else {
#pragma unroll
                for (int co = 0; co < CO; ++co) lds[el][co] += acc[co];
            }
        }
        __syncthreads();
    }
    if (chunk == 0 && active) {
#pragma unroll
        for (int co = 0; co < CO; ++co)
            y[(((size_t)b * CO + co) * H_ + r_out) * W_ + c_out] = lds[el][co] + bias[co];
    }
}

__global__ __launch_bounds__(256) void conv_corner(
    const float* __restrict__ x,
    const float* __restrict__ w_bl, const float* __restrict__ w_br,
    const float* __restrict__ w_tl, const float* __restrict__ w_tr,
    const float* __restrict__ bias, float* __restrict__ y)
{
    const int b      = blockIdx.x;
    const int corner = threadIdx.x >> 6;
    const int co     = threadIdx.x & 63;
    const float* w = (corner == 0) ? w_bl : (corner == 1) ? w_br
                   : (corner == 2) ? w_tl : w_tr;
    const int rr    = (corner < 2) ? (H_ - 3) : 0;
    const int cc    = (corner & 1) ? (W_ - 3) : 0;
    const int r_out = (corner < 2) ? 0 : (H_ - 1);
    const int c_out = (corner & 1) ? (W_ - 1) : 0;
    const float* xb = x + (size_t)b * CI * H_ * W_;
    float a = 0.f;
    for (int ci = 0; ci < CI; ++ci) {
        const float* xp = xb + ((size_t)ci * H_ + rr) * W_ + cc;
        const float* wp = w + ((size_t)co * CI + ci) * 9;
#pragma unroll
        for (int kr = 0; kr < 3; ++kr)
#pragma unroll
            for (int kc = 0; kc < 3; ++kc)
                a = fmaf(xp[kr * W_ + kc], wp[kr * 3 + kc], a);
    }
    y[(((size_t)b * CO + co) * H_ + r_out) * W_ + c_out] = a + bias[co];
}

__global__ __launch_bounds__(256) void stats_kernel(
    const float* __restrict__ y, float* __restrict__ ws)
{
    const int bid   = blockIdx.x;
    const int chunk = bid & 3;
    const int g     = (bid >> 2) & 15;
    const int b     = bid >> 6;
    const float* p  = y + ((size_t)(b * 64 + g * 4 + chunk)) * (H_ * W_);
    float s = 0.f, q = 0.f;
    for (int i = threadIdx.x; i < (H_ * W_ / 4); i += 256) {
        float4 v = reinterpret_cast<const float4*>(p)[i];
        s += v.x + v.y + v.z + v.w;
        q += v.x * v.x + v.y * v.y + v.z * v.z + v.w * v.w;
    }
#pragma unroll
    for (int off = 32; off; off >>= 1) {
        s += __shfl_down(s, off);
        q += __shfl_down(q, off);
    }
    __shared__ float red[8];
    const int wid = threadIdx.x >> 6;
    if ((threadIdx.x & 63) == 0) { red[wid * 2] = s; red[wid * 2 + 1] = q; }
    __syncthreads();
    if (threadIdx.x == 0) {
        ws[bid * 2]     = red[0] + red[2] + red[4] + red[6];
        ws[bid * 2 + 1] = red[1] + red[3] + red[5] + red[7];
    }
}

__global__ __launch_bounds__(256) void norm_stats(
    float* __restrict__ y, const float* __restrict__ st,
    const float* __restrict__ gamma, const float* __restrict__ beta)
{
    const size_t t = (size_t)blockIdx.x * 256 + threadIdx.x;
    const size_t e = t * 4;
    const int b  = (int)(e >> 22);
    const int ch = (int)((e >> 16) & 63);
    const int g  = ch >> 2;
    const int sb = ((b * 16 + g) * 4) * 2;
    const float S = st[sb] + st[sb + 2] + st[sb + 4] + st[sb + 6];
    const float Q = st[sb + 1] + st[sb + 3] + st[sb + 5] + st[sb + 7];
    const float inv_n = 1.0f / (4.0f * H_ * W_);
    const float mean  = S * inv_n;
    const float var   = Q * inv_n - mean * mean;
    const float rstd  = rsqrtf(var + EPS_);
    const float ga = gamma[ch] * rstd;
    const float be = beta[ch] - mean * ga;
    float4 v = reinterpret_cast<float4*>(y)[t];
    float u;
    u = v.x * ga + be; v.x = selu_f(u);
    u = v.y * ga + be; v.y = selu_f(u);
    u = v.z * ga + be; v.z = selu_f(u);
    u = v.w * ga + be; v.w = selu_f(u);
    reinterpret_cast<float4*>(y)[t] = v;
}

extern "C" void kernel_launch(void* const* d_in, const int* in_sizes, int n_in,
                              void* d_out, int out_size, void* d_ws, size_t ws_size,
                              hipStream_t stream) {
    const float* x       = (const float*)d_in[0];
    const float* w_int   = (const float*)d_in[1];
    const float* w_tl    = (const float*)d_in[2];
    const float* w_tr    = (const float*)d_in[3];
    const float* w_bl    = (const float*)d_in[4];
    const float* w_br    = (const float*)d_in[5];
    const float* w_top   = (const float*)d_in[6];
    const float* w_bot   = (const float*)d_in[7];
    const float* w_left  = (const float*)d_in[8];
    const float* w_right = (const float*)d_in[9];
    const float* bias    = (const float*)d_in[10];
    const float* gamma   = (const float*)d_in[11];
    const float* beta    = (const float*)d_in[12];

    float* out = (float*)d_out;

    const size_t XPRE    = 67108864ull;                // bf16 x NHWC
    const size_t YBF     = 67108864ull;                // bf16 y NCHW
    const size_t WPRE    = 73728ull;                   // bf16 w_int
    const size_t WEDGE   = 1179648ull;                 // fp32 [8][9][16][64][4]
    const size_t WEDGEBF = 589824ull;                  // bf16 copy of wedge
    const size_t PART    = 524288ull;                  // [8][512][16][2] f32
    const size_t MV      = 1024ull;                    // [8][16][2] f32
    const size_t NEED    = XPRE + YBF + WPRE + WEDGE + WEDGEBF + PART + MV;

    if (ws_size >= NEED) {
        char* base = (char*)d_ws;
        unsigned short* xpre    = (unsigned short*)base;                    base += XPRE;
        unsigned short* ybf     = (unsigned short*)base;                    base += YBF;
        unsigned short* wpre    = (unsigned short*)base;                    base += WPRE;
        float*          wedge   = (float*)base;                             base += WEDGE;
        unsigned short* wedgebf = (unsigned short*)base;                    base += WEDGEBF;
        float*          part    = (float*)base;                             base += PART;
        float*          mv      = (float*)base;

        prepass_weights<<<dim3(81), 256, 0, stream>>>(
            w_int, w_bl, w_br, w_tl, w_tr, w_bot, w_top, w_left, w_right,
            wpre, wedge, wedgebf);
        prepass_x<<<dim3(256, 8), 256, 0, stream>>>(x, xpre);
        conv_mfma<<<dim3(8, 32, 8), 512, 0, stream>>>(xpre, wpre, bias, ybf, part);
        conv_edge4<<<dim3(8, 4, 16), 256, 0, stream>>>(xpre, wedgebf, bias, ybf, part);
        conv_corner2<<<dim3(8), 256, 0, stream>>>(xpre, wedge, bias, ybf, part);
        stats_reduce<<<dim3(8), 256, 0, stream>>>(part, mv);
        norm_bf<<<dim3(16384), 256, 0, stream>>>(ybf, out, mv, gamma, beta);
    } else {
        float* stats = (float*)d_ws;
        conv_main<<<dim3(H_, B_), 256, 0, stream>>>(x, w_int, bias, out);
        conv_edge<<<dim3(B_, 4, 4), 256, 0, stream>>>(x, w_bot, w_top, w_left, w_right, bias, out);
        conv_corner<<<dim3(B_), 256, 0, stream>>>(x, w_bl, w_br, w_tl, w_tr, bias, out);
        stats_kernel<<<dim3(512), 256, 0, stream>>>(out, stats);
        norm_stats<<<dim3(32768), 256, 0, stream>>>(out, stats, gamma, beta);
    }
}

// Round 15
// 196.701 us; speedup vs baseline: 5.8300x; 1.1528x over previous
//
#include <hip/hip_runtime.h>

#define B_ 8
#define CI 64
#define CO 64
#define H_ 256
#define W_ 256
#define EPS_ 1e-5f

#define SELU_SCALE 1.0507009873554805f
#define SELU_SA    1.7580993408473766f

typedef __attribute__((ext_vector_type(8))) short short8;
typedef __attribute__((ext_vector_type(4))) float f32x4;
typedef unsigned int u32;

__device__ __forceinline__ unsigned short f2bf(float f) {
    unsigned int u = __float_as_uint(f);
    u = (u + 0x7fffu + ((u >> 16) & 1u)) >> 16;
    return (unsigned short)u;
}
__device__ __forceinline__ float bf2f(unsigned short h) {
    return __uint_as_float(((unsigned)h) << 16);
}
__device__ __forceinline__ float selu_f(float u) {
    return (u > 0.f) ? SELU_SCALE * u : SELU_SA * (__expf(u) - 1.f);
}
__device__ __forceinline__ void gload_lds16(const void* g, void* l) {
    __builtin_amdgcn_global_load_lds(
        (const __attribute__((address_space(1))) u32*)g,
        (__attribute__((address_space(3))) u32*)l, 16, 0, 0);
}

// ===========================================================================
// Weight prepass: 81 blocks = 9 wids x 9 pos.
// wpre9[wid][pos][co][ci ^ ((co&7)<<3)] bf16; wid 0=bl 1=br 2=tl 3=tr 4=bot
// 5=top 6=left 7=right 8=interior.  wedge fp32 [wid<8][pos][ci4][co][4].
// ===========================================================================
__global__ __launch_bounds__(256) void prepass_weights(
    const float* __restrict__ w_int,
    const float* __restrict__ w_bl, const float* __restrict__ w_br,
    const float* __restrict__ w_tl, const float* __restrict__ w_tr,
    const float* __restrict__ w_bot, const float* __restrict__ w_top,
    const float* __restrict__ w_left, const float* __restrict__ w_right,
    unsigned short* __restrict__ wpre9, float* __restrict__ wedge)
{
    const int blk = blockIdx.x, t = threadIdx.x;
    const int wid = blk / 9, pos = blk % 9;
    const float* src = (wid == 0) ? w_bl : (wid == 1) ? w_br
                     : (wid == 2) ? w_tl : (wid == 3) ? w_tr
                     : (wid == 4) ? w_bot : (wid == 5) ? w_top
                     : (wid == 6) ? w_left : (wid == 7) ? w_right : w_int;
    for (int k = 0; k < 16; ++k) {
        const int lin = k * 256 + t;
        // bf16 MFMA layout
        const int co = lin >> 6, cip = lin & 63;
        const int ci = cip ^ ((co & 7) << 3);
        wpre9[(size_t)wid * 36864 + pos * 4096 + lin] = f2bf(src[(co * 64 + ci) * 9 + pos]);
        // fp32 corner layout
        if (wid < 8) {
            const int c4 = lin >> 8, co2 = (lin >> 2) & 63, j = lin & 3;
            const int ci2 = c4 * 4 + j;
            wedge[(size_t)wid * 36864 + pos * 4096 + lin] = src[(co2 * 64 + ci2) * 9 + pos];
        }
    }
}

// ===========================================================================
// Prepass: x fp32 NCHW -> bf16 NHWC swizzled: xpre[b][row][col][ci^((col&7)<<3)]
// ===========================================================================
__global__ __launch_bounds__(256) void prepass_x(
    const float* __restrict__ x, unsigned short* __restrict__ xpre)
{
    __shared__ unsigned short ls[256 * 72];
    const int row = blockIdx.x, b = blockIdx.y;
    const int t = threadIdx.x;
    const int colq = t >> 2;
    const float* xb = x + ((size_t)(b * 64) * 256 + row) * 256;

    for (int sp = 0; sp < 4; ++sp) {
        const int cibase = sp * 16 + (t & 3) * 4;
        float4 v[4];
#pragma unroll
        for (int e = 0; e < 4; ++e)
            v[e] = *(const float4*)(xb + (size_t)(cibase + e) * 65536 + colq * 4);
#pragma unroll
        for (int jj = 0; jj < 4; ++jj) {
            const int col = colq * 4 + jj;
            const int sw  = (col & 7) << 3;
            ushort4 pk;
            pk.x = f2bf((&v[0].x)[jj]);
            pk.y = f2bf((&v[1].x)[jj]);
            pk.z = f2bf((&v[2].x)[jj]);
            pk.w = f2bf((&v[3].x)[jj]);
            *(ushort4*)&ls[col * 72 + (cibase ^ sw)] = pk;
        }
    }
    __syncthreads();
    unsigned short* xp = xpre + ((size_t)(b * 256 + row)) * 256 * 64;
    for (int q = 0; q < 8; ++q) {
        const int lin = q * 256 + t;
        const int col = lin >> 3, k = lin & 7;
        *(uint4*)(xp + col * 64 + k * 8) = *(const uint4*)&ls[col * 72 + k * 8];
    }
}

// ===========================================================================
// MFMA interior conv + fused masked group-stats partials (R11 v7 proven).
// ===========================================================================
__global__ __launch_bounds__(512, 4) void conv_mfma(
    const unsigned short* __restrict__ xpre, const unsigned short* __restrict__ wpre,
    const float* __restrict__ bias, unsigned short* __restrict__ ybf,
    float* __restrict__ part)
{
    __shared__ unsigned short xs[10 * 40 * 64];   // 51200 B
    __shared__ unsigned short wl3[3][4096];       // 12288 B
    __shared__ float sred[8][16][2];              // 1024 B
    const int t = threadIdx.x, w = t >> 6, lane = t & 63;
    const int b = blockIdx.z, r0 = blockIdx.y * 8, c0 = blockIdx.x * 32;

    for (int L = w; L < 50; L += 8) {
        const int j = L / 5, i = L % 5;
        int rr = r0 - 1 + j; rr = rr < 0 ? 0 : (rr > 255 ? 255 : rr);
        int col = c0 - 2 + i * 8 + (lane >> 3);
        col = col < 0 ? 0 : (col > 255 ? 255 : col);
        const char* src = (const char*)xpre +
            ((size_t)((b * 256 + rr) * 256 + col)) * 128 + (lane & 7) * 16;
        gload_lds16(src, (char*)xs + j * 5120 + i * 1024);
    }
    gload_lds16((const char*)wpre + 0 * 8192 + w * 1024 + lane * 16,
                (char*)wl3[0] + w * 1024);
    gload_lds16((const char*)wpre + 1 * 8192 + w * 1024 + lane * 16,
                (char*)wl3[1] + w * 1024);

    const int l15 = lane & 15, lg = lane >> 4;
    const int sw15 = (l15 & 7) << 3;

    int jb[3];
#pragma unroll
    for (int kr = 0; kr < 3; ++kr) jb[kr] = (w + kr) * 5120;
    int offb[3][2][2];
#pragma unroll
    for (int kc = 0; kc < 3; ++kc)
#pragma unroll
        for (int n = 0; n < 2; ++n) {
            const int s = n * 16 + l15 + kc + 1;
#pragma unroll
            for (int ks = 0; ks < 2; ++ks) {
                const int cib = ks * 32 + lg * 8;
                offb[kc][n][ks] = s * 128 + ((cib ^ (((s + 6) & 7) << 3)) << 1);
            }
        }
    int afo[2][4];
#pragma unroll
    for (int ks = 0; ks < 2; ++ks)
#pragma unroll
        for (int m = 0; m < 4; ++m) {
            const int cib = ks * 32 + lg * 8;
            afo[ks][m] = (m * 16 + l15) * 128 + ((cib ^ sw15) << 1);
        }

    f32x4 acc[4][2];
#pragma unroll
    for (int m = 0; m < 4; ++m)
#pragma unroll
        for (int n = 0; n < 2; ++n)
            acc[m][n] = (f32x4){0.f, 0.f, 0.f, 0.f};

#pragma unroll
    for (int pos = 0; pos < 9; ++pos) {
        if (pos < 8) asm volatile("s_waitcnt vmcnt(1)" ::: "memory");
        else         asm volatile("s_waitcnt vmcnt(0)" ::: "memory");
        __builtin_amdgcn_s_barrier();
        __builtin_amdgcn_sched_barrier(0);
        if (pos + 2 <= 8)
            gload_lds16((const char*)wpre + (pos + 2) * 8192 + w * 1024 + lane * 16,
                        (char*)wl3[(pos + 2) % 3] + w * 1024);
        const int kr = pos / 3, kc = pos % 3;
        const char* wbuf = (const char*)wl3[pos % 3];
#pragma unroll
        for (int ks = 0; ks < 2; ++ks) {
            short8 bf[2], af[4];
#pragma unroll
            for (int n = 0; n < 2; ++n)
                bf[n] = *(const short8*)((const char*)xs + jb[kr] + offb[kc][n][ks]);
#pragma unroll
            for (int m = 0; m < 4; ++m)
                af[m] = *(const short8*)(wbuf + afo[ks][m]);
            __builtin_amdgcn_s_setprio(1);
#pragma unroll
            for (int m = 0; m < 4; ++m)
#pragma unroll
                for (int n = 0; n < 2; ++n)
                    acc[m][n] = __builtin_amdgcn_mfma_f32_16x16x32_bf16(
                        af[m], bf[n], acc[m][n], 0, 0, 0);
            __builtin_amdgcn_s_setprio(0);
        }
    }

    const int r = r0 + w;
    const bool rmask = (r != 0) && (r != 255);
    float s4[4] = {0.f, 0.f, 0.f, 0.f}, q4[4] = {0.f, 0.f, 0.f, 0.f};
#pragma unroll
    for (int m = 0; m < 4; ++m)
#pragma unroll
        for (int n = 0; n < 2; ++n) {
            const int c = c0 + n * 16 + l15;
            const bool pmask = rmask && (c != 0) && (c != 255);
#pragma unroll
            for (int reg = 0; reg < 4; ++reg) {
                const int co = m * 16 + lg * 4 + reg;
                const float v = acc[m][n][reg] + bias[co];
                ybf[(((size_t)b * 64 + co) * 256 + r) * 256 + c] = f2bf(v);
                if (pmask) { s4[m] += v; q4[m] += v * v; }
            }
        }
#pragma unroll
    for (int off = 1; off < 16; off <<= 1)
#pragma unroll
        for (int m = 0; m < 4; ++m) {
            s4[m] += __shfl_xor(s4[m], off);
            q4[m] += __shfl_xor(q4[m], off);
        }
    if (l15 == 0) {
#pragma unroll
        for (int m = 0; m < 4; ++m) {
            sred[w][m * 4 + lg][0] = s4[m];
            sred[w][m * 4 + lg][1] = q4[m];
        }
    }
    __syncthreads();
    if (t < 32) {
        const int g = t & 15, sel = t >> 4;
        float v = 0.f;
#pragma unroll
        for (int ww = 0; ww < 8; ++ww) v += sred[ww][g][sel];
        const int slot = blockIdx.y * 8 + blockIdx.x;      // 0..255
        part[((size_t)(b * 512 + slot) * 16 + g) * 2 + sel] = v;
    }
}

// ===========================================================================
// MFMA edge rows 0 / 255 (bot/top weights). grid (8 seg, 2 edge, 8 b),
// block 256 = 4 waves, wave = co-tile. Reuses conv_mfma's xs/offb layout
// with 3 input rows. Corners (c=0,255) masked; overwritten by corner kernel.
// Stats slots 256..271.
// ===========================================================================
__global__ __launch_bounds__(256) void conv_edge_tb(
    const unsigned short* __restrict__ xpre, const unsigned short* __restrict__ wpre9,
    const float* __restrict__ bias, unsigned short* __restrict__ ybf,
    float* __restrict__ part)
{
    __shared__ unsigned short xs3[3 * 40 * 64];   // 15360 B
    __shared__ unsigned short wl3[3][4096];       // 12288 B
    __shared__ float ered[16][2];
    const int t = threadIdx.x, w = t >> 6, lane = t & 63;
    const int seg = blockIdx.x, edge = blockIdx.y, b = blockIdx.z;
    const int c0 = seg * 32;
    const int wid = 4 + edge;                     // 4=bot(row0), 5=top(row255)

    // x first, then weights (vmcnt(2) leaves only W1 in flight)
    for (int L = w; L < 15; L += 4) {
        const int j = L / 5, i = L % 5;
        const int rr = (edge == 0) ? (253 + j) : j;
        int col = c0 - 2 + i * 8 + (lane >> 3);
        col = col < 0 ? 0 : (col > 255 ? 255 : col);
        gload_lds16((const char*)xpre +
                        ((size_t)((b * 256 + rr) * 256 + col)) * 128 + (lane & 7) * 16,
                    (char*)xs3 + j * 5120 + i * 1024);
    }
    const char* wsrc = (const char*)wpre9 + (size_t)wid * 73728;
#pragma unroll
    for (int c = 0; c < 2; ++c)
        gload_lds16(wsrc + 0 * 8192 + (w * 2 + c) * 1024 + lane * 16,
                    (char*)wl3[0] + (w * 2 + c) * 1024);
#pragma unroll
    for (int c = 0; c < 2; ++c)
        gload_lds16(wsrc + 1 * 8192 + (w * 2 + c) * 1024 + lane * 16,
                    (char*)wl3[1] + (w * 2 + c) * 1024);

    const int l15 = lane & 15, lg = lane >> 4;
    const int sw15 = (l15 & 7) << 3;
    int offb[3][2][2];
#pragma unroll
    for (int kc = 0; kc < 3; ++kc)
#pragma unroll
        for (int n = 0; n < 2; ++n) {
            const int s = n * 16 + l15 + kc + 1;
#pragma unroll
            for (int ks = 0; ks < 2; ++ks) {
                const int cib = ks * 32 + lg * 8;
                offb[kc][n][ks] = s * 128 + ((cib ^ (((s + 6) & 7) << 3)) << 1);
            }
        }
    int afo[2];
#pragma unroll
    for (int ks = 0; ks < 2; ++ks) {
        const int cib = ks * 32 + lg * 8;
        afo[ks] = (w * 16 + l15) * 128 + ((cib ^ sw15) << 1);
    }

    f32x4 acc[2];
    acc[0] = (f32x4){0.f, 0.f, 0.f, 0.f};
    acc[1] = (f32x4){0.f, 0.f, 0.f, 0.f};

#pragma unroll
    for (int pos = 0; pos < 9; ++pos) {
        if (pos < 8) asm volatile("s_waitcnt vmcnt(2)" ::: "memory");
        else         asm volatile("s_waitcnt vmcnt(0)" ::: "memory");
        __builtin_amdgcn_s_barrier();
        __builtin_amdgcn_sched_barrier(0);
        if (pos + 2 <= 8) {
#pragma unroll
            for (int c = 0; c < 2; ++c)
                gload_lds16(wsrc + (pos + 2) * 8192 + (w * 2 + c) * 1024 + lane * 16,
                            (char*)wl3[(pos + 2) % 3] + (w * 2 + c) * 1024);
        }
        const int kr = pos / 3, kc = pos % 3;
        const char* wbuf = (const char*)wl3[pos % 3];
#pragma unroll
        for (int ks = 0; ks < 2; ++ks) {
            short8 bf[2];
#pragma unroll
            for (int n = 0; n < 2; ++n)
                bf[n] = *(const short8*)((const char*)xs3 + kr * 5120 + offb[kc][n][ks]);
            const short8 af = *(const short8*)(wbuf + afo[ks]);
#pragma unroll
            for (int n = 0; n < 2; ++n)
                acc[n] = __builtin_amdgcn_mfma_f32_16x16x32_bf16(af, bf[n], acc[n], 0, 0, 0);
        }
    }

    const int r_out = (edge == 0) ? 0 : 255;
    float s = 0.f, q = 0.f;
#pragma unroll
    for (int n = 0; n < 2; ++n) {
        const int c = c0 + n * 16 + l15;
        const bool pmask = (c != 0) && (c != 255);
#pragma unroll
        for (int reg = 0; reg < 4; ++reg) {
            const int co = w * 16 + lg * 4 + reg;
            const float v = acc[n][reg] + bias[co];
            ybf[(((size_t)b * 64 + co) * 256 + r_out) * 256 + c] = f2bf(v);
            if (pmask) { s += v; q += v * v; }
        }
    }
    s += __shfl_xor(s, 1); q += __shfl_xor(q, 1);
    s += __shfl_xor(s, 2); q += __shfl_xor(q, 2);
    s += __shfl_xor(s, 4); q += __shfl_xor(q, 4);
    s += __shfl_xor(s, 8); q += __shfl_xor(q, 8);
    if (l15 == 0) { ered[w * 4 + lg][0] = s; ered[w * 4 + lg][1] = q; }
    __syncthreads();
    if (t < 32) {
        const int g = t & 15, sel = t >> 4;
        const int slot = 256 + edge * 8 + seg;
        part[((size_t)(b * 512 + slot) * 16 + g) * 2 + sel] = ered[g][sel];
    }
}

// ===========================================================================
// MFMA edge cols 0 / 255 (left/right weights). grid (4 seg, 2 edge, 8 b),
// block 256 = 4 waves = co-tiles; N = 64 output rows (4 n-tiles).
// x tile: 66 rows x 3 cols x 64 ci bf16, row stride padded to 400 B
// (100 dwords = 4 mod 32 banks -> 2-way, free). Rows 0/255 masked.
// Stats slots 272..279.
// ===========================================================================
__global__ __launch_bounds__(256) void conv_edge_lr(
    const unsigned short* __restrict__ xpre, const unsigned short* __restrict__ wpre9,
    const float* __restrict__ bias, unsigned short* __restrict__ ybf,
    float* __restrict__ part)
{
    __shared__ unsigned short xr[66 * 200];       // 26400 B (400 B / row)
    __shared__ unsigned short wl3[3][4096];       // 12288 B
    __shared__ float ered[16][2];
    const int t = threadIdx.x, w = t >> 6, lane = t & 63;
    const int seg = blockIdx.x, edge = blockIdx.y, b = blockIdx.z;
    const int r0 = seg * 64;
    const int wid = 6 + edge;                     // 6=left(col0), 7=right(col255)
    const int colbase = edge ? 253 : 0;

    // x: reg->LDS (padded layout), then weights async
    for (int u = t; u < 1584; u += 256) {
        const int row = u / 24, rem = u % 24;
        const int cl = rem >> 3, sub = rem & 7;
        int rr = r0 - 1 + row; rr = rr < 0 ? 0 : (rr > 255 ? 255 : rr);
        const int col = colbase + cl;
        const uint4 v = *(const uint4*)(xpre +
            ((size_t)((b * 256 + rr) * 256 + col)) * 64 + sub * 8);
        *(uint4*)((char*)xr + row * 400 + cl * 128 + sub * 16) = v;
    }
    const char* wsrc = (const char*)wpre9 + (size_t)wid * 73728;
#pragma unroll
    for (int c = 0; c < 2; ++c)
        gload_lds16(wsrc + 0 * 8192 + (w * 2 + c) * 1024 + lane * 16,
                    (char*)wl3[0] + (w * 2 + c) * 1024);
#pragma unroll
    for (int c = 0; c < 2; ++c)
        gload_lds16(wsrc + 1 * 8192 + (w * 2 + c) * 1024 + lane * 16,
                    (char*)wl3[1] + (w * 2 + c) * 1024);
    asm volatile("s_waitcnt lgkmcnt(0)" ::: "memory");   // xr writes done

    const int l15 = lane & 15, lg = lane >> 4;
    const int sw15 = (l15 & 7) << 3;
    int offlr[3][2];
#pragma unroll
    for (int kc = 0; kc < 3; ++kc) {
        const int key = (colbase + kc) & 7;
#pragma unroll
        for (int ks = 0; ks < 2; ++ks) {
            const int cib = ks * 32 + lg * 8;
            offlr[kc][ks] = kc * 128 + ((cib ^ (key << 3)) << 1);
        }
    }
    int rowb[4];
#pragma unroll
    for (int n = 0; n < 4; ++n) rowb[n] = (n * 16 + l15) * 400;
    int afo[2];
#pragma unroll
    for (int ks = 0; ks < 2; ++ks) {
        const int cib = ks * 32 + lg * 8;
        afo[ks] = (w * 16 + l15) * 128 + ((cib ^ sw15) << 1);
    }

    f32x4 acc[4];
#pragma unroll
    for (int n = 0; n < 4; ++n) acc[n] = (f32x4){0.f, 0.f, 0.f, 0.f};

#pragma unroll
    for (int pos = 0; pos < 9; ++pos) {
        if (pos < 8) asm volatile("s_waitcnt vmcnt(2)" ::: "memory");
        else         asm volatile("s_waitcnt vmcnt(0)" ::: "memory");
        __builtin_amdgcn_s_barrier();
        __builtin_amdgcn_sched_barrier(0);
        if (pos + 2 <= 8) {
#pragma unroll
            for (int c = 0; c < 2; ++c)
                gload_lds16(wsrc + (pos + 2) * 8192 + (w * 2 + c) * 1024 + lane * 16,
                            (char*)wl3[(pos + 2) % 3] + (w * 2 + c) * 1024);
        }
        const int kr = pos / 3, kc = pos % 3;
        const char* wbuf = (const char*)wl3[pos % 3];
#pragma unroll
        for (int ks = 0; ks < 2; ++ks) {
            const short8 af = *(const short8*)(wbuf + afo[ks]);
#pragma unroll
            for (int n = 0; n < 4; ++n) {
                const short8 bf = *(const short8*)((const char*)xr +
                                    rowb[n] + kr * 400 + offlr[kc][ks]);
                acc[n] = __builtin_amdgcn_mfma_f32_16x16x32_bf16(af, bf, acc[n], 0, 0, 0);
            }
        }
    }

    const int c_out = edge ? 255 : 0;
    float s = 0.f, q = 0.f;
#pragma unroll
    for (int n = 0; n < 4; ++n) {
        const int r = r0 + n * 16 + l15;
        const bool pmask = (r != 0) && (r != 255);
#pragma unroll
        for (int reg = 0; reg < 4; ++reg) {
            const int co = w * 16 + lg * 4 + reg;
            const float v = acc[n][reg] + bias[co];
            ybf[(((size_t)b * 64 + co) * 256 + r) * 256 + c_out] = f2bf(v);
            if (pmask) { s += v; q += v * v; }
        }
    }
    s += __shfl_xor(s, 1); q += __shfl_xor(q, 1);
    s += __shfl_xor(s, 2); q += __shfl_xor(q, 2);
    s += __shfl_xor(s, 4); q += __shfl_xor(q, 4);
    s += __shfl_xor(s, 8); q += __shfl_xor(q, 8);
    if (l15 == 0) { ered[w * 4 + lg][0] = s; ered[w * 4 + lg][1] = q; }
    __syncthreads();
    if (t < 32) {
        const int g = t & 15, sel = t >> 4;
        const int slot = 272 + edge * 4 + seg;
        part[((size_t)(b * 512 + slot) * 16 + g) * 2 + sel] = ered[g][sel];
    }
}

// ===========================================================================
// Corners, pipelined (float4 w + ushort4 x, 4 partial accs). Slot 280.
// ===========================================================================
__global__ __launch_bounds__(256) void conv_corner3(
    const unsigned short* __restrict__ xpre, const float* __restrict__ wedge,
    const float* __restrict__ bias, unsigned short* __restrict__ ybf,
    float* __restrict__ part)
{
    __shared__ float cred[4][16][2];
    const int b = blockIdx.x, t = threadIdx.x;
    const int corner = t >> 6, co = t & 63;
    const int wid  = corner;                       // 0=bl 1=br 2=tl 3=tr
    const int row0 = (corner < 2) ? 253 : 0;
    const int col0 = (corner & 1) ? 253 : 0;
    const int r_out = (corner < 2) ? 0 : 255;
    const int c_out = (corner & 1) ? 255 : 0;

    const float* wbase = wedge + (size_t)wid * 36864;
    float a0 = 0.f, a1 = 0.f, a2 = 0.f, a3 = 0.f;
#pragma unroll 1
    for (int pos = 0; pos < 9; ++pos) {
        const int kr = pos / 3, kc = pos % 3;
        const int row = row0 + kr, col = col0 + kc;
        const unsigned short* xp = xpre + ((size_t)((b * 256 + row) * 256 + col)) * 64;
        const int sw = (col & 7) << 3;
#pragma unroll
        for (int c4 = 0; c4 < 16; ++c4) {
            const float4 wv = *(const float4*)(wbase + pos * 4096 + c4 * 256 + co * 4);
            const ushort4 xv = *(const ushort4*)(xp + ((c4 * 4) ^ sw));
            a0 = fmaf(wv.x, bf2f(xv.x), a0);
            a1 = fmaf(wv.y, bf2f(xv.y), a1);
            a2 = fmaf(wv.z, bf2f(xv.z), a2);
            a3 = fmaf(wv.w, bf2f(xv.w), a3);
        }
    }
    const float v = (a0 + a1) + (a2 + a3) + bias[co];
    ybf[(((size_t)b * 64 + co) * 256 + r_out) * 256 + c_out] = f2bf(v);
    float s = v, q = v * v;
    s += __shfl_xor(s, 1); q += __shfl_xor(q, 1);
    s += __shfl_xor(s, 2); q += __shfl_xor(q, 2);
    if ((co & 3) == 0) { cred[corner][co >> 2][0] = s; cred[corner][co >> 2][1] = q; }
    __syncthreads();
    if (t < 32) {
        const int g = t & 15, sel = t >> 4;
        const float r = cred[0][g][sel] + cred[1][g][sel] +
                        cred[2][g][sel] + cred[3][g][sel];
        part[((size_t)(b * 512 + 280) * 16 + g) * 2 + sel] = r;
    }
}

// ===========================================================================
// Reduce 281 partial slots -> mean/rstd per (b, group).
// ===========================================================================
__global__ __launch_bounds__(256) void stats_reduce(
    const float* __restrict__ part, float* __restrict__ mv)
{
    __shared__ float sred[16][16][2];
    const int b = blockIdx.x, t = threadIdx.x;
    const int g = t & 15, chunk = t >> 4;
    float s = 0.f, q = 0.f;
    for (int k = 0; k < 18; ++k) {
        const int slot = chunk * 18 + k;
        if (slot < 281) {
            const size_t base = ((size_t)(b * 512 + slot) * 16 + g) * 2;
            s += part[base]; q += part[base + 1];
        }
    }
    sred[chunk][g][0] = s; sred[chunk][g][1] = q;
    __syncthreads();
    if (t < 16) {
        float S = 0.f, Q = 0.f;
#pragma unroll
        for (int c = 0; c < 16; ++c) { S += sred[c][t][0]; Q += sred[c][t][1]; }
        const float inv_n = 1.0f / (4.0f * 65536.0f);
        const float mean = S * inv_n;
        const float var  = Q * inv_n - mean * mean;
        mv[(b * 16 + t) * 2]     = mean;
        mv[(b * 16 + t) * 2 + 1] = rsqrtf(var + EPS_);
    }
}

// ===========================================================================
// GroupNorm + SELU: read bf16 ybf, write fp32 out. 8 elems/thread.
// ===========================================================================
__global__ __launch_bounds__(256) void norm_bf(
    const unsigned short* __restrict__ ybf, float* __restrict__ out,
    const float* __restrict__ mv,
    const float* __restrict__ gamma, const float* __restrict__ beta)
{
    const size_t tt = (size_t)blockIdx.x * 256 + threadIdx.x;
    const size_t e = tt * 8;
    const int b  = (int)(e >> 22);
    const int ch = (int)((e >> 16) & 63);
    const int g  = ch >> 2;
    const float mean = mv[(b * 16 + g) * 2];
    const float rstd = mv[(b * 16 + g) * 2 + 1];
    const float ga = gamma[ch] * rstd;
    const float be = beta[ch] - mean * ga;

    const uint4 v = *(const uint4*)(ybf + e);
    float f[8];
    f[0] = __uint_as_float(v.x << 16); f[1] = __uint_as_float(v.x & 0xffff0000u);
    f[2] = __uint_as_float(v.y << 16); f[3] = __uint_as_float(v.y & 0xffff0000u);
    f[4] = __uint_as_float(v.z << 16); f[5] = __uint_as_float(v.z & 0xffff0000u);
    f[6] = __uint_as_float(v.w << 16); f[7] = __uint_as_float(v.w & 0xffff0000u);
    float4 o0, o1;
    o0.x = selu_f(f[0] * ga + be); o0.y = selu_f(f[1] * ga + be);
    o0.z = selu_f(f[2] * ga + be); o0.w = selu_f(f[3] * ga + be);
    o1.x = selu_f(f[4] * ga + be); o1.y = selu_f(f[5] * ga + be);
    o1.z = selu_f(f[6] * ga + be); o1.w = selu_f(f[7] * ga + be);
    *(float4*)(out + e)     = o0;
    *(float4*)(out + e + 4) = o1;
}

// ===========================================================================
// Fallback path (round-1 proven kernels) for small ws.
// ===========================================================================
__global__ __launch_bounds__(256) void conv_main(
    const float* __restrict__ x, const float* __restrict__ w,
    const float* __restrict__ bias, float* __restrict__ y)
{
    const int c = threadIdx.x;
    const int r = blockIdx.x;
    const int b = blockIdx.y;
    const int rr = (r == 0) ? (H_ - 3) : ((r == H_ - 1) ? 0 : (r - 1));
    const int cc = min(max(c - 1, 0), W_ - 3);
    float acc[CO];
#pragma unroll
    for (int co = 0; co < CO; ++co) acc[co] = 0.f;
    const float* xb = x + (size_t)b * CI * H_ * W_;
    for (int ci = 0; ci < CI; ++ci) {
        const float* xp = xb + ((size_t)ci * H_ + rr) * W_ + cc;
        float xv[9];
#pragma unroll
        for (int kr = 0; kr < 3; ++kr)
#pragma unroll
            for (int kc = 0; kc < 3; ++kc)
                xv[kr * 3 + kc] = xp[kr * W_ + kc];
        const float* wci = w + ci * 9;
#pragma unroll
        for (int co = 0; co < CO; ++co) {
            const float* wp = wci + co * (CI * 9);
            float a = acc[co];
#pragma unroll
            for (int k = 0; k < 9; ++k) a = fmaf(xv[k], wp[k], a);
            acc[co] = a;
        }
    }
#pragma unroll
    for (int co = 0; co < CO; ++co)
        y[(((size_t)b * CO + co) * H_ + r) * W_ + c] = acc[co] + bias[co];
}

__global__ __launch_bounds__(256) void conv_edge(
    const float* __restrict__ x,
    const float* __restrict__ w_bot, const float* __restrict__ w_top,
    const float* __restrict__ w_left, const float* __restrict__ w_right,
    const float* __restrict__ bias, float* __restrict__ y)
{
    const int b     = blockIdx.x;
    const int edge  = blockIdx.y;
    const int seg   = blockIdx.z;
    const int el    = threadIdx.x & 63;
    const int chunk = threadIdx.x >> 6;
    const int e     = seg * 64 + el;
    const bool active = (e < 254);
    const int ec    = active ? e : 253;
    const float* w = (edge == 0) ? w_bot : (edge == 1) ? w_top
                   : (edge == 2) ? w_left : w_right;
    int r_out, c_out, rr, cc;
    if (edge == 0)      { r_out = 0;      c_out = 1 + ec; rr = H_ - 3; cc = ec; }
    else if (edge == 1) { r_out = H_ - 1; c_out = 1 + ec; rr = 0;      cc = ec; }
    else if (edge == 2) { r_out = 1 + ec; c_out = 0;      rr = ec;     cc = 0; }
    else                { r_out = 1 + ec; c_out = W_ - 1; rr = ec;     cc = W_ - 3; }
    float acc[CO];
#pragma unroll
    for (int co = 0; co < CO; ++co) acc[co] = 0.f;
    const float* xb = x + (size_t)b * CI * H_ * W_;
    const int ci0 = chunk * 16;
    for (int ci = ci0; ci < ci0 + 16; ++ci) {
        const float* xp = xb + ((size_t)ci * H_ + rr) * W_ + cc;
        float xv[9];
#pragma unroll
        for (int kr = 0; kr < 3; ++kr)
#pragma unroll
            for (int kc = 0; kc < 3; ++kc)
                xv[kr * 3 + kc] = xp[kr * W_ + kc];
#pragma unroll
        for (int co = 0; co < CO; ++co) {
            const float* wp = w + co * (CI * 9) + ci * 9;
            float a = acc[co];
#pragma unroll
            for (int k = 0; k < 9; ++k) a = fmaf(xv[k], wp[k], a);
            acc[co] = a;
        }
    }
    __shared__ float lds[64][65];
    for (int s = 0; s < 4; ++s) {
        if (chunk == s) {
            if (s == 0) {
#pragma unroll
                for (int co = 0; co < CO; ++co) lds[el][co] = acc[co];
            } else {
#pragma unroll
                for (int co = 0; co < CO; ++co) lds[el][co] += acc[co];
            }
        }
        __syncthreads();
    }
    if (chunk == 0 && active) {
#pragma unroll
        for (int co = 0; co < CO; ++co)
            y[(((size_t)b * CO + co) * H_ + r_out) * W_ + c_out] = lds[el][co] + bias[co];
    }
}

__global__ __launch_bounds__(256) void conv_corner(
    const float* __restrict__ x,
    const float* __restrict__ w_bl, const float* __restrict__ w_br,
    const float* __restrict__ w_tl, const float* __restrict__ w_tr,
    const float* __restrict__ bias, float* __restrict__ y)
{
    const int b      = blockIdx.x;
    const int corner = threadIdx.x >> 6;
    const int co     = threadIdx.x & 63;
    const float* w = (corner == 0) ? w_bl : (corner == 1) ? w_br
                   : (corner == 2) ? w_tl : w_tr;
    const int rr    = (corner < 2) ? (H_ - 3) : 0;
    const int cc    = (corner & 1) ? (W_ - 3) : 0;
    const int r_out = (corner < 2) ? 0 : (H_ - 1);
    const int c_out = (corner & 1) ? (W_ - 1) : 0;
    const float* xb = x + (size_t)b * CI * H_ * W_;
    float a = 0.f;
    for (int ci = 0; ci < CI; ++ci) {
        const float* xp = xb + ((size_t)ci * H_ + rr) * W_ + cc;
        const float* wp = w + ((size_t)co * CI + ci) * 9;
#pragma unroll
        for (int kr = 0; kr < 3; ++kr)
#pragma unroll
            for (int kc = 0; kc < 3; ++kc)
                a = fmaf(xp[kr * W_ + kc], wp[kr * 3 + kc], a);
    }
    y[(((size_t)b * CO + co) * H_ + r_out) * W_ + c_out] = a + bias[co];
}

__global__ __launch_bounds__(256) void stats_kernel(
    const float* __restrict__ y, float* __restrict__ ws)
{
    const int bid   = blockIdx.x;
    const int chunk = bid & 3;
    const int g     = (bid >> 2) & 15;
    const int b     = bid >> 6;
    const float* p  = y + ((size_t)(b * 64 + g * 4 + chunk)) * (H_ * W_);
    float s = 0.f, q = 0.f;
    for (int i = threadIdx.x; i < (H_ * W_ / 4); i += 256) {
        float4 v = reinterpret_cast<const float4*>(p)[i];
        s += v.x + v.y + v.z + v.w;
        q += v.x * v.x + v.y * v.y + v.z * v.z + v.w * v.w;
    }
#pragma unroll
    for (int off = 32; off; off >>= 1) {
        s += __shfl_down(s, off);
        q += __shfl_down(q, off);
    }
    __shared__ float red[8];
    const int wid = threadIdx.x >> 6;
    if ((threadIdx.x & 63) == 0) { red[wid * 2] = s; red[wid * 2 + 1] = q; }
    __syncthreads();
    if (threadIdx.x == 0) {
        ws[bid * 2]     = red[0] + red[2] + red[4] + red[6];
        ws[bid * 2 + 1] = red[1] + red[3] + red[5] + red[7];
    }
}

__global__ __launch_bounds__(256) void norm_stats(
    float* __restrict__ y, const float* __restrict__ st,
    const float* __restrict__ gamma, const float* __restrict__ beta)
{
    const size_t t = (size_t)blockIdx.x * 256 + threadIdx.x;
    const size_t e = t * 4;
    const int b  = (int)(e >> 22);
    const int ch = (int)((e >> 16) & 63);
    const int g  = ch >> 2;
    const int sb = ((b * 16 + g) * 4) * 2;
    const float S = st[sb] + st[sb + 2] + st[sb + 4] + st[sb + 6];
    const float Q = st[sb + 1] + st[sb + 3] + st[sb + 5] + st[sb + 7];
    const float inv_n = 1.0f / (4.0f * H_ * W_);
    const float mean  = S * inv_n;
    const float var   = Q * inv_n - mean * mean;
    const float rstd  = rsqrtf(var + EPS_);
    const float ga = gamma[ch] * rstd;
    const float be = beta[ch] - mean * ga;
    float4 v = reinterpret_cast<float4*>(y)[t];
    float u;
    u = v.x * ga + be; v.x = selu_f(u);
    u = v.y * ga + be; v.y = selu_f(u);
    u = v.z * ga + be; v.z = selu_f(u);
    u = v.w * ga + be; v.w = selu_f(u);
    reinterpret_cast<float4*>(y)[t] = v;
}

extern "C" void kernel_launch(void* const* d_in, const int* in_sizes, int n_in,
                              void* d_out, int out_size, void* d_ws, size_t ws_size,
                              hipStream_t stream) {
    const float* x       = (const float*)d_in[0];
    const float* w_int   = (const float*)d_in[1];
    const float* w_tl    = (const float*)d_in[2];
    const float* w_tr    = (const float*)d_in[3];
    const float* w_bl    = (const float*)d_in[4];
    const float* w_br    = (const float*)d_in[5];
    const float* w_top   = (const float*)d_in[6];
    const float* w_bot   = (const float*)d_in[7];
    const float* w_left  = (const float*)d_in[8];
    const float* w_right = (const float*)d_in[9];
    const float* bias    = (const float*)d_in[10];
    const float* gamma   = (const float*)d_in[11];
    const float* beta    = (const float*)d_in[12];

    float* out = (float*)d_out;

    const size_t XPRE  = 67108864ull;                  // bf16 x NHWC
    const size_t YBF   = 67108864ull;                  // bf16 y NCHW
    const size_t WPRE9 = 663552ull;                    // bf16 [9][9][64][64]
    const size_t WEDGE = 1179648ull;                   // fp32 [8][9][16][64][4]
    const size_t PART  = 524288ull;                    // [8][512][16][2] f32
    const size_t MV    = 1024ull;
    const size_t NEED  = XPRE + YBF + WPRE9 + WEDGE + PART + MV;

    if (ws_size >= NEED) {
        char* base = (char*)d_ws;
        unsigned short* xpre  = (unsigned short*)base;  base += XPRE;
        unsigned short* ybf   = (unsigned short*)base;  base += YBF;
        unsigned short* wpre9 = (unsigned short*)base;  base += WPRE9;
        float*          wedge = (float*)base;           base += WEDGE;
        float*          part  = (float*)base;           base += PART;
        float*          mv    = (float*)base;

        prepass_weights<<<dim3(81), 256, 0, stream>>>(
            w_int, w_bl, w_br, w_tl, w_tr, w_bot, w_top, w_left, w_right,
            wpre9, wedge);
        prepass_x<<<dim3(256, 8), 256, 0, stream>>>(x, xpre);
        conv_mfma<<<dim3(8, 32, 8), 512, 0, stream>>>(
            xpre, wpre9 + 8 * 36864, bias, ybf, part);
        conv_edge_tb<<<dim3(8, 2, 8), 256, 0, stream>>>(xpre, wpre9, bias, ybf, part);
        conv_edge_lr<<<dim3(4, 2, 8), 256, 0, stream>>>(xpre, wpre9, bias, ybf, part);
        conv_corner3<<<dim3(8), 256, 0, stream>>>(xpre, wedge, bias, ybf, part);
        stats_reduce<<<dim3(8), 256, 0, stream>>>(part, mv);
        norm_bf<<<dim3(16384), 256, 0, stream>>>(ybf, out, mv, gamma, beta);
    } else {
        float* stats = (float*)d_ws;
        conv_main<<<dim3(H_, B_), 256, 0, stream>>>(x, w_int, bias, out);
        conv_edge<<<dim3(B_, 4, 4), 256, 0, stream>>>(x, w_bot, w_top, w_left, w_right, bias, out);
        conv_corner<<<dim3(B_), 256, 0, stream>>>(x, w_bl, w_br, w_tl, w_tr, bias, out);
        stats_kernel<<<dim3(512), 256, 0, stream>>>(out, stats);
        norm_stats<<<dim3(32768), 256, 0, stream>>>(out, stats, gamma, beta);
    }
}

// Round 16
// 172.400 us; speedup vs baseline: 6.6518x; 1.1410x over previous
//
#include <hip/hip_runtime.h>

#define B_ 8
#define CI 64
#define CO 64
#define H_ 256
#define W_ 256
#define EPS_ 1e-5f

#define SELU_SCALE 1.0507009873554805f
#define SELU_SA    1.7580993408473766f

typedef __attribute__((ext_vector_type(8))) short short8;
typedef __attribute__((ext_vector_type(4))) float f32x4;
typedef unsigned int u32;

__device__ __forceinline__ unsigned short f2bf(float f) {
    unsigned int u = __float_as_uint(f);
    u = (u + 0x7fffu + ((u >> 16) & 1u)) >> 16;
    return (unsigned short)u;
}
__device__ __forceinline__ float bf2f(unsigned short h) {
    return __uint_as_float(((unsigned)h) << 16);
}
__device__ __forceinline__ float selu_f(float u) {
    return (u > 0.f) ? SELU_SCALE * u : SELU_SA * (__expf(u) - 1.f);
}
__device__ __forceinline__ void gload_lds16(const void* g, void* l) {
    __builtin_amdgcn_global_load_lds(
        (const __attribute__((address_space(1))) u32*)g,
        (__attribute__((address_space(3))) u32*)l, 16, 0, 0);
}

// ===========================================================================
// Weight prepass: 81 blocks = 9 wids x 9 pos.
// wpre9[wid][pos][co][ci ^ ((co&7)<<3)] bf16; wid 0=bl 1=br 2=tl 3=tr 4=bot
// 5=top 6=left 7=right 8=interior.  wedge fp32 [wid<8][pos][ci4][co][4].
// ===========================================================================
__global__ __launch_bounds__(256) void prepass_weights(
    const float* __restrict__ w_int,
    const float* __restrict__ w_bl, const float* __restrict__ w_br,
    const float* __restrict__ w_tl, const float* __restrict__ w_tr,
    const float* __restrict__ w_bot, const float* __restrict__ w_top,
    const float* __restrict__ w_left, const float* __restrict__ w_right,
    unsigned short* __restrict__ wpre9, float* __restrict__ wedge)
{
    const int blk = blockIdx.x, t = threadIdx.x;
    const int wid = blk / 9, pos = blk % 9;
    const float* src = (wid == 0) ? w_bl : (wid == 1) ? w_br
                     : (wid == 2) ? w_tl : (wid == 3) ? w_tr
                     : (wid == 4) ? w_bot : (wid == 5) ? w_top
                     : (wid == 6) ? w_left : (wid == 7) ? w_right : w_int;
    for (int k = 0; k < 16; ++k) {
        const int lin = k * 256 + t;
        const int co = lin >> 6, cip = lin & 63;
        const int ci = cip ^ ((co & 7) << 3);
        wpre9[(size_t)wid * 36864 + pos * 4096 + lin] = f2bf(src[(co * 64 + ci) * 9 + pos]);
        if (wid < 8) {
            const int c4 = lin >> 8, co2 = (lin >> 2) & 63, j = lin & 3;
            const int ci2 = c4 * 4 + j;
            wedge[(size_t)wid * 36864 + pos * 4096 + lin] = src[(co2 * 64 + ci2) * 9 + pos];
        }
    }
}

// ===========================================================================
// Prepass: x fp32 NCHW -> bf16 NHWC swizzled: xpre[b][row][col][ci^((col&7)<<3)]
// ===========================================================================
__global__ __launch_bounds__(256) void prepass_x(
    const float* __restrict__ x, unsigned short* __restrict__ xpre)
{
    __shared__ unsigned short ls[256 * 72];
    const int row = blockIdx.x, b = blockIdx.y;
    const int t = threadIdx.x;
    const int colq = t >> 2;
    const float* xb = x + ((size_t)(b * 64) * 256 + row) * 256;

    for (int sp = 0; sp < 4; ++sp) {
        const int cibase = sp * 16 + (t & 3) * 4;
        float4 v[4];
#pragma unroll
        for (int e = 0; e < 4; ++e)
            v[e] = *(const float4*)(xb + (size_t)(cibase + e) * 65536 + colq * 4);
#pragma unroll
        for (int jj = 0; jj < 4; ++jj) {
            const int col = colq * 4 + jj;
            const int sw  = (col & 7) << 3;
            ushort4 pk;
            pk.x = f2bf((&v[0].x)[jj]);
            pk.y = f2bf((&v[1].x)[jj]);
            pk.z = f2bf((&v[2].x)[jj]);
            pk.w = f2bf((&v[3].x)[jj]);
            *(ushort4*)&ls[col * 72 + (cibase ^ sw)] = pk;
        }
    }
    __syncthreads();
    unsigned short* xp = xpre + ((size_t)(b * 256 + row)) * 256 * 64;
    for (int q = 0; q < 8; ++q) {
        const int lin = q * 256 + t;
        const int col = lin >> 3, k = lin & 7;
        *(uint4*)(xp + col * 64 + k * 8) = *(const uint4*)&ls[col * 72 + k * 8];
    }
}

// ===========================================================================
// Fused conv: grid (8, 36, 8).
//   by < 32 : interior MFMA tile (R11 v7 pipeline), stores only r,c in 1..254.
//   by >= 32: job = (by-32)*8 + bx:
//       job 0..15  TB edge rows 0/255 (MFMA), stores c in 1..254
//       job 16..23 LR edge cols 0/255 (MFMA), stores r in 1..254
//       job 24     4 corner pixels (VALU)
//       job >24    idle
// Stats partials: interior 0..255, TB 256..271, LR 272..279, corner 280.
// ===========================================================================
__global__ __launch_bounds__(512, 4) void conv_all(
    const unsigned short* __restrict__ xpre, const unsigned short* __restrict__ wpre9,
    const float* __restrict__ wedge, const float* __restrict__ bias,
    unsigned short* __restrict__ ybf, float* __restrict__ part)
{
    __shared__ unsigned short xs[10 * 40 * 64];   // 51200 B (borders alias)
    __shared__ unsigned short wl3[3][4096];       // 12288 B
    __shared__ float sred[8][16][2];              // 1024 B (borders alias)
    const int t = threadIdx.x, w = t >> 6, lane = t & 63;
    const int b = blockIdx.z;
    const int l15 = lane & 15, lg = lane >> 4;
    const int sw15 = (l15 & 7) << 3;

    if (blockIdx.y < 32) {
        // ================= interior =================
        const unsigned short* wpre = wpre9 + 8 * 36864;
        const int r0 = blockIdx.y * 8, c0 = blockIdx.x * 32;

        for (int L = w; L < 50; L += 8) {
            const int j = L / 5, i = L % 5;
            int rr = r0 - 1 + j; rr = rr < 0 ? 0 : (rr > 255 ? 255 : rr);
            int col = c0 - 2 + i * 8 + (lane >> 3);
            col = col < 0 ? 0 : (col > 255 ? 255 : col);
            gload_lds16((const char*)xpre +
                            ((size_t)((b * 256 + rr) * 256 + col)) * 128 + (lane & 7) * 16,
                        (char*)xs + j * 5120 + i * 1024);
        }
        gload_lds16((const char*)wpre + 0 * 8192 + w * 1024 + lane * 16,
                    (char*)wl3[0] + w * 1024);
        gload_lds16((const char*)wpre + 1 * 8192 + w * 1024 + lane * 16,
                    (char*)wl3[1] + w * 1024);

        int jb[3];
#pragma unroll
        for (int kr = 0; kr < 3; ++kr) jb[kr] = (w + kr) * 5120;
        int offb[3][2][2];
#pragma unroll
        for (int kc = 0; kc < 3; ++kc)
#pragma unroll
            for (int n = 0; n < 2; ++n) {
                const int s = n * 16 + l15 + kc + 1;
#pragma unroll
                for (int ks = 0; ks < 2; ++ks) {
                    const int cib = ks * 32 + lg * 8;
                    offb[kc][n][ks] = s * 128 + ((cib ^ (((s + 6) & 7) << 3)) << 1);
                }
            }
        int afo[2][4];
#pragma unroll
        for (int ks = 0; ks < 2; ++ks)
#pragma unroll
            for (int m = 0; m < 4; ++m) {
                const int cib = ks * 32 + lg * 8;
                afo[ks][m] = (m * 16 + l15) * 128 + ((cib ^ sw15) << 1);
            }

        f32x4 acc[4][2];
#pragma unroll
        for (int m = 0; m < 4; ++m)
#pragma unroll
            for (int n = 0; n < 2; ++n)
                acc[m][n] = (f32x4){0.f, 0.f, 0.f, 0.f};

#pragma unroll
        for (int pos = 0; pos < 9; ++pos) {
            if (pos < 8) asm volatile("s_waitcnt vmcnt(1)" ::: "memory");
            else         asm volatile("s_waitcnt vmcnt(0)" ::: "memory");
            __builtin_amdgcn_s_barrier();
            __builtin_amdgcn_sched_barrier(0);
            if (pos + 2 <= 8)
                gload_lds16((const char*)wpre + (pos + 2) * 8192 + w * 1024 + lane * 16,
                            (char*)wl3[(pos + 2) % 3] + w * 1024);
            const int kr = pos / 3, kc = pos % 3;
            const char* wbuf = (const char*)wl3[pos % 3];
#pragma unroll
            for (int ks = 0; ks < 2; ++ks) {
                short8 bf[2], af[4];
#pragma unroll
                for (int n = 0; n < 2; ++n)
                    bf[n] = *(const short8*)((const char*)xs + jb[kr] + offb[kc][n][ks]);
#pragma unroll
                for (int m = 0; m < 4; ++m)
                    af[m] = *(const short8*)(wbuf + afo[ks][m]);
                __builtin_amdgcn_s_setprio(1);
#pragma unroll
                for (int m = 0; m < 4; ++m)
#pragma unroll
                    for (int n = 0; n < 2; ++n)
                        acc[m][n] = __builtin_amdgcn_mfma_f32_16x16x32_bf16(
                            af[m], bf[n], acc[m][n], 0, 0, 0);
                __builtin_amdgcn_s_setprio(0);
            }
        }

        const int r = r0 + w;
        const bool rmask = (r != 0) && (r != 255);
        float s4[4] = {0.f, 0.f, 0.f, 0.f}, q4[4] = {0.f, 0.f, 0.f, 0.f};
#pragma unroll
        for (int m = 0; m < 4; ++m)
#pragma unroll
            for (int n = 0; n < 2; ++n) {
                const int c = c0 + n * 16 + l15;
                const bool pmask = rmask && (c != 0) && (c != 255);
#pragma unroll
                for (int reg = 0; reg < 4; ++reg) {
                    const int co = m * 16 + lg * 4 + reg;
                    const float v = acc[m][n][reg] + bias[co];
                    if (pmask) {
                        ybf[(((size_t)b * 64 + co) * 256 + r) * 256 + c] = f2bf(v);
                        s4[m] += v; q4[m] += v * v;
                    }
                }
            }
#pragma unroll
        for (int off = 1; off < 16; off <<= 1)
#pragma unroll
            for (int m = 0; m < 4; ++m) {
                s4[m] += __shfl_xor(s4[m], off);
                q4[m] += __shfl_xor(q4[m], off);
            }
        if (l15 == 0) {
#pragma unroll
            for (int m = 0; m < 4; ++m) {
                sred[w][m * 4 + lg][0] = s4[m];
                sred[w][m * 4 + lg][1] = q4[m];
            }
        }
        __syncthreads();
        if (t < 32) {
            const int g = t & 15, sel = t >> 4;
            float v = 0.f;
#pragma unroll
            for (int ww = 0; ww < 8; ++ww) v += sred[ww][g][sel];
            const int slot = blockIdx.y * 8 + blockIdx.x;
            part[((size_t)(b * 512 + slot) * 16 + g) * 2 + sel] = v;
        }
        return;
    }

    // ================= borders =================
    const int job = (blockIdx.y - 32) * 8 + blockIdx.x;
    if (job > 24) return;

    if (job < 16) {
        // ---- TB: rows 0 / 255; 8 waves: cot = w&3 (co-tile), nh = w>>2 ----
        const int edge = job >> 3, seg = job & 7;
        const int c0 = seg * 32;
        const char* wsrc = (const char*)wpre9 + (size_t)(4 + edge) * 73728;
        for (int L = w; L < 15; L += 8) {
            const int j = L / 5, i = L % 5;
            const int rr = (edge == 0) ? (253 + j) : j;
            int col = c0 - 2 + i * 8 + (lane >> 3);
            col = col < 0 ? 0 : (col > 255 ? 255 : col);
            gload_lds16((const char*)xpre +
                            ((size_t)((b * 256 + rr) * 256 + col)) * 128 + (lane & 7) * 16,
                        (char*)xs + j * 5120 + i * 1024);
        }
        gload_lds16(wsrc + 0 * 8192 + w * 1024 + lane * 16, (char*)wl3[0] + w * 1024);
        gload_lds16(wsrc + 1 * 8192 + w * 1024 + lane * 16, (char*)wl3[1] + w * 1024);

        const int cot = w & 3, nh = w >> 2;
        int offb2[3][2];
#pragma unroll
        for (int kc = 0; kc < 3; ++kc) {
            const int s = nh * 16 + l15 + kc + 1;
#pragma unroll
            for (int ks = 0; ks < 2; ++ks) {
                const int cib = ks * 32 + lg * 8;
                offb2[kc][ks] = s * 128 + ((cib ^ (((s + 6) & 7) << 3)) << 1);
            }
        }
        int afo2[2];
#pragma unroll
        for (int ks = 0; ks < 2; ++ks) {
            const int cib = ks * 32 + lg * 8;
            afo2[ks] = (cot * 16 + l15) * 128 + ((cib ^ sw15) << 1);
        }
        f32x4 acc0 = (f32x4){0.f, 0.f, 0.f, 0.f};

#pragma unroll
        for (int pos = 0; pos < 9; ++pos) {
            if (pos < 8) asm volatile("s_waitcnt vmcnt(1)" ::: "memory");
            else         asm volatile("s_waitcnt vmcnt(0)" ::: "memory");
            __builtin_amdgcn_s_barrier();
            __builtin_amdgcn_sched_barrier(0);
            if (pos + 2 <= 8)
                gload_lds16(wsrc + (pos + 2) * 8192 + w * 1024 + lane * 16,
                            (char*)wl3[(pos + 2) % 3] + w * 1024);
            const int kr = pos / 3, kc = pos % 3;
            const char* wbuf = (const char*)wl3[pos % 3];
#pragma unroll
            for (int ks = 0; ks < 2; ++ks) {
                const short8 bf = *(const short8*)((const char*)xs + kr * 5120 + offb2[kc][ks]);
                const short8 af = *(const short8*)(wbuf + afo2[ks]);
                acc0 = __builtin_amdgcn_mfma_f32_16x16x32_bf16(af, bf, acc0, 0, 0, 0);
            }
        }

        const int r_out = edge ? 255 : 0;
        const int c = c0 + nh * 16 + l15;
        const bool pmask = (c != 0) && (c != 255);
        float s = 0.f, q = 0.f;
#pragma unroll
        for (int reg = 0; reg < 4; ++reg) {
            const int co = cot * 16 + lg * 4 + reg;
            const float v = acc0[reg] + bias[co];
            if (pmask) {
                ybf[(((size_t)b * 64 + co) * 256 + r_out) * 256 + c] = f2bf(v);
                s += v; q += v * v;
            }
        }
        s += __shfl_xor(s, 1); q += __shfl_xor(q, 1);
        s += __shfl_xor(s, 2); q += __shfl_xor(q, 2);
        s += __shfl_xor(s, 4); q += __shfl_xor(q, 4);
        s += __shfl_xor(s, 8); q += __shfl_xor(q, 8);
        float* sb = (float*)sred;                        // [8][4][2]
        if (l15 == 0) { sb[(w * 4 + lg) * 2] = s; sb[(w * 4 + lg) * 2 + 1] = q; }
        __syncthreads();
        if (t < 32) {
            const int g = t & 15, sel = t >> 4;
            const int ct = g >> 2, sub = g & 3;
            const float v = sb[(ct * 4 + sub) * 2 + sel] + sb[((ct + 4) * 4 + sub) * 2 + sel];
            part[((size_t)(b * 512 + 256 + job) * 16 + g) * 2 + sel] = v;
        }
    } else if (job < 24) {
        // ---- LR: cols 0 / 255; 8 waves: cot = w&3, np = w>>2 (2 n-tiles) ----
        const int jj = job - 16;
        const int edge = jj >> 2, seg = jj & 3;
        const int r0 = seg * 64;
        const int colbase = edge ? 253 : 0;
        unsigned short* xr = xs;                         // 66 rows x 400 B
        for (int u = t; u < 1584; u += 512) {
            const int row = u / 24, rem = u % 24;
            const int cl = rem >> 3, sub = rem & 7;
            int rr = r0 - 1 + row; rr = rr < 0 ? 0 : (rr > 255 ? 255 : rr);
            const int col = colbase + cl;
            const uint4 v = *(const uint4*)(xpre +
                ((size_t)((b * 256 + rr) * 256 + col)) * 64 + sub * 8);
            *(uint4*)((char*)xr + row * 400 + cl * 128 + sub * 16) = v;
        }
        const char* wsrc = (const char*)wpre9 + (size_t)(6 + edge) * 73728;
        gload_lds16(wsrc + 0 * 8192 + w * 1024 + lane * 16, (char*)wl3[0] + w * 1024);
        gload_lds16(wsrc + 1 * 8192 + w * 1024 + lane * 16, (char*)wl3[1] + w * 1024);
        asm volatile("s_waitcnt lgkmcnt(0)" ::: "memory");

        const int cot = w & 3, np = w >> 2;
        int offlr[3][2];
#pragma unroll
        for (int kc = 0; kc < 3; ++kc) {
            const int key = (colbase + kc) & 7;
#pragma unroll
            for (int ks = 0; ks < 2; ++ks) {
                const int cib = ks * 32 + lg * 8;
                offlr[kc][ks] = kc * 128 + ((cib ^ (key << 3)) << 1);
            }
        }
        int rowb2[2];
#pragma unroll
        for (int j = 0; j < 2; ++j) rowb2[j] = ((np * 2 + j) * 16 + l15) * 400;
        int afo2[2];
#pragma unroll
        for (int ks = 0; ks < 2; ++ks) {
            const int cib = ks * 32 + lg * 8;
            afo2[ks] = (cot * 16 + l15) * 128 + ((cib ^ sw15) << 1);
        }
        f32x4 accA = (f32x4){0.f, 0.f, 0.f, 0.f};
        f32x4 accB = (f32x4){0.f, 0.f, 0.f, 0.f};

#pragma unroll
        for (int pos = 0; pos < 9; ++pos) {
            if (pos < 8) asm volatile("s_waitcnt vmcnt(1)" ::: "memory");
            else         asm volatile("s_waitcnt vmcnt(0)" ::: "memory");
            __builtin_amdgcn_s_barrier();
            __builtin_amdgcn_sched_barrier(0);
            if (pos + 2 <= 8)
                gload_lds16(wsrc + (pos + 2) * 8192 + w * 1024 + lane * 16,
                            (char*)wl3[(pos + 2) % 3] + w * 1024);
            const int kr = pos / 3, kc = pos % 3;
            const char* wbuf = (const char*)wl3[pos % 3];
#pragma unroll
            for (int ks = 0; ks < 2; ++ks) {
                const short8 af = *(const short8*)(wbuf + afo2[ks]);
                const short8 bfA = *(const short8*)((const char*)xr + rowb2[0] + kr * 400 + offlr[kc][ks]);
                const short8 bfB = *(const short8*)((const char*)xr + rowb2[1] + kr * 400 + offlr[kc][ks]);
                accA = __builtin_amdgcn_mfma_f32_16x16x32_bf16(af, bfA, accA, 0, 0, 0);
                accB = __builtin_amdgcn_mfma_f32_16x16x32_bf16(af, bfB, accB, 0, 0, 0);
            }
        }

        const int c_out = edge ? 255 : 0;
        float s = 0.f, q = 0.f;
#pragma unroll
        for (int j = 0; j < 2; ++j) {
            const int r = r0 + (np * 2 + j) * 16 + l15;
            const bool pmask = (r != 0) && (r != 255);
            const f32x4 a = j ? accB : accA;
#pragma unroll
            for (int reg = 0; reg < 4; ++reg) {
                const int co = cot * 16 + lg * 4 + reg;
                const float v = a[reg] + bias[co];
                if (pmask) {
                    ybf[(((size_t)b * 64 + co) * 256 + r) * 256 + c_out] = f2bf(v);
                    s += v; q += v * v;
                }
            }
        }
        s += __shfl_xor(s, 1); q += __shfl_xor(q, 1);
        s += __shfl_xor(s, 2); q += __shfl_xor(q, 2);
        s += __shfl_xor(s, 4); q += __shfl_xor(q, 4);
        s += __shfl_xor(s, 8); q += __shfl_xor(q, 8);
        float* sb = (float*)sred;                        // [8][4][2]
        if (l15 == 0) { sb[(w * 4 + lg) * 2] = s; sb[(w * 4 + lg) * 2 + 1] = q; }
        __syncthreads();
        if (t < 32) {
            const int g = t & 15, sel = t >> 4;
            const int ct = g >> 2, sub = g & 3;
            const float v = sb[(ct * 4 + sub) * 2 + sel] + sb[((ct + 4) * 4 + sub) * 2 + sel];
            part[((size_t)(b * 512 + 272 + jj) * 16 + g) * 2 + sel] = v;
        }
    } else {
        // ---- corners (job 24): waves 0..3 = corners, waves 4..7 idle ----
        float* cred = (float*)sred;                      // [4][16][2]
        if (w < 4) {
            const int corner = w, co = lane;
            const int row0 = (corner < 2) ? 253 : 0;
            const int col0 = (corner & 1) ? 253 : 0;
            const int r_out = (corner < 2) ? 0 : 255;
            const int c_out = (corner & 1) ? 255 : 0;
            const float* wbase = wedge + (size_t)corner * 36864;
            float a0 = 0.f, a1 = 0.f, a2 = 0.f, a3 = 0.f;
#pragma unroll 1
            for (int pos = 0; pos < 9; ++pos) {
                const int kr = pos / 3, kc = pos % 3;
                const int row = row0 + kr, col = col0 + kc;
                const unsigned short* xp = xpre + ((size_t)((b * 256 + row) * 256 + col)) * 64;
                const int sw = (col & 7) << 3;
#pragma unroll
                for (int c4 = 0; c4 < 16; ++c4) {
                    const float4 wv = *(const float4*)(wbase + pos * 4096 + c4 * 256 + co * 4);
                    const ushort4 xv = *(const ushort4*)(xp + ((c4 * 4) ^ sw));
                    a0 = fmaf(wv.x, bf2f(xv.x), a0);
                    a1 = fmaf(wv.y, bf2f(xv.y), a1);
                    a2 = fmaf(wv.z, bf2f(xv.z), a2);
                    a3 = fmaf(wv.w, bf2f(xv.w), a3);
                }
            }
            const float v = (a0 + a1) + (a2 + a3) + bias[co];
            ybf[(((size_t)b * 64 + co) * 256 + r_out) * 256 + c_out] = f2bf(v);
            float s = v, q = v * v;
            s += __shfl_xor(s, 1); q += __shfl_xor(q, 1);
            s += __shfl_xor(s, 2); q += __shfl_xor(q, 2);
            if ((co & 3) == 0) {
                cred[(corner * 16 + (co >> 2)) * 2]     = s;
                cred[(corner * 16 + (co >> 2)) * 2 + 1] = q;
            }
        }
        __syncthreads();
        if (t < 32) {
            const int g = t & 15, sel = t >> 4;
            const float r = cred[(0 * 16 + g) * 2 + sel] + cred[(1 * 16 + g) * 2 + sel] +
                            cred[(2 * 16 + g) * 2 + sel] + cred[(3 * 16 + g) * 2 + sel];
            part[((size_t)(b * 512 + 280) * 16 + g) * 2 + sel] = r;
        }
    }
}

// ===========================================================================
// Reduce 281 partial slots -> mean/rstd per (b, group).
// ===========================================================================
__global__ __launch_bounds__(256) void stats_reduce(
    const float* __restrict__ part, float* __restrict__ mv)
{
    __shared__ float sred[16][16][2];
    const int b = blockIdx.x, t = threadIdx.x;
    const int g = t & 15, chunk = t >> 4;
    float s = 0.f, q = 0.f;
    for (int k = 0; k < 18; ++k) {
        const int slot = chunk * 18 + k;
        if (slot < 281) {
            const size_t base = ((size_t)(b * 512 + slot) * 16 + g) * 2;
            s += part[base]; q += part[base + 1];
        }
    }
    sred[chunk][g][0] = s; sred[chunk][g][1] = q;
    __syncthreads();
    if (t < 16) {
        float S = 0.f, Q = 0.f;
#pragma unroll
        for (int c = 0; c < 16; ++c) { S += sred[c][t][0]; Q += sred[c][t][1]; }
        const float inv_n = 1.0f / (4.0f * 65536.0f);
        const float mean = S * inv_n;
        const float var  = Q * inv_n - mean * mean;
        mv[(b * 16 + t) * 2]     = mean;
        mv[(b * 16 + t) * 2 + 1] = rsqrtf(var + EPS_);
    }
}

// ===========================================================================
// GroupNorm + SELU: read bf16 ybf, write fp32 out. 8 elems/thread.
// ===========================================================================
__global__ __launch_bounds__(256) void norm_bf(
    const unsigned short* __restrict__ ybf, float* __restrict__ out,
    const float* __restrict__ mv,
    const float* __restrict__ gamma, const float* __restrict__ beta)
{
    const size_t tt = (size_t)blockIdx.x * 256 + threadIdx.x;
    const size_t e = tt * 8;
    const int b  = (int)(e >> 22);
    const int ch = (int)((e >> 16) & 63);
    const int g  = ch >> 2;
    const float mean = mv[(b * 16 + g) * 2];
    const float rstd = mv[(b * 16 + g) * 2 + 1];
    const float ga = gamma[ch] * rstd;
    const float be = beta[ch] - mean * ga;

    const uint4 v = *(const uint4*)(ybf + e);
    float f[8];
    f[0] = __uint_as_float(v.x << 16); f[1] = __uint_as_float(v.x & 0xffff0000u);
    f[2] = __uint_as_float(v.y << 16); f[3] = __uint_as_float(v.y & 0xffff0000u);
    f[4] = __uint_as_float(v.z << 16); f[5] = __uint_as_float(v.z & 0xffff0000u);
    f[6] = __uint_as_float(v.w << 16); f[7] = __uint_as_float(v.w & 0xffff0000u);
    float4 o0, o1;
    o0.x = selu_f(f[0] * ga + be); o0.y = selu_f(f[1] * ga + be);
    o0.z = selu_f(f[2] * ga + be); o0.w = selu_f(f[3] * ga + be);
    o1.x = selu_f(f[4] * ga + be); o1.y = selu_f(f[5] * ga + be);
    o1.z = selu_f(f[6] * ga + be); o1.w = selu_f(f[7] * ga + be);
    *(float4*)(out + e)     = o0;
    *(float4*)(out + e + 4) = o1;
}

// ===========================================================================
// Fallback path (round-1 proven kernels) for small ws.
// ===========================================================================
__global__ __launch_bounds__(256) void conv_main(
    const float* __restrict__ x, const float* __restrict__ w,
    const float* __restrict__ bias, float* __restrict__ y)
{
    const int c = threadIdx.x;
    const int r = blockIdx.x;
    const int b = blockIdx.y;
    const int rr = (r == 0) ? (H_ - 3) : ((r == H_ - 1) ? 0 : (r - 1));
    const int cc = min(max(c - 1, 0), W_ - 3);
    float acc[CO];
#pragma unroll
    for (int co = 0; co < CO; ++co) acc[co] = 0.f;
    const float* xb = x + (size_t)b * CI * H_ * W_;
    for (int ci = 0; ci < CI; ++ci) {
        const float* xp = xb + ((size_t)ci * H_ + rr) * W_ + cc;
        float xv[9];
#pragma unroll
        for (int kr = 0; kr < 3; ++kr)
#pragma unroll
            for (int kc = 0; kc < 3; ++kc)
                xv[kr * 3 + kc] = xp[kr * W_ + kc];
        const float* wci = w + ci * 9;
#pragma unroll
        for (int co = 0; co < CO; ++co) {
            const float* wp = wci + co * (CI * 9);
            float a = acc[co];
#pragma unroll
            for (int k = 0; k < 9; ++k) a = fmaf(xv[k], wp[k], a);
            acc[co] = a;
        }
    }
#pragma unroll
    for (int co = 0; co < CO; ++co)
        y[(((size_t)b * CO + co) * H_ + r) * W_ + c] = acc[co] + bias[co];
}

__global__ __launch_bounds__(256) void conv_edge(
    const float* __restrict__ x,
    const float* __restrict__ w_bot, const float* __restrict__ w_top,
    const float* __restrict__ w_left, const float* __restrict__ w_right,
    const float* __restrict__ bias, float* __restrict__ y)
{
    const int b     = blockIdx.x;
    const int edge  = blockIdx.y;
    const int seg   = blockIdx.z;
    const int el    = threadIdx.x & 63;
    const int chunk = threadIdx.x >> 6;
    const int e     = seg * 64 + el;
    const bool active = (e < 254);
    const int ec    = active ? e : 253;
    const float* w = (edge == 0) ? w_bot : (edge == 1) ? w_top
                   : (edge == 2) ? w_left : w_right;
    int r_out, c_out, rr, cc;
    if (edge == 0)      { r_out = 0;      c_out = 1 + ec; rr = H_ - 3; cc = ec; }
    else if (edge == 1) { r_out = H_ - 1; c_out = 1 + ec; rr = 0;      cc = ec; }
    else if (edge == 2) { r_out = 1 + ec; c_out = 0;      rr = ec;     cc = 0; }
    else                { r_out = 1 + ec; c_out = W_ - 1; rr = ec;     cc = W_ - 3; }
    float acc[CO];
#pragma unroll
    for (int co = 0; co < CO; ++co) acc[co] = 0.f;
    const float* xb = x + (size_t)b * CI * H_ * W_;
    const int ci0 = chunk * 16;
    for (int ci = ci0; ci < ci0 + 16; ++ci) {
        const float* xp = xb + ((size_t)ci * H_ + rr) * W_ + cc;
        float xv[9];
#pragma unroll
        for (int kr = 0; kr < 3; ++kr)
#pragma unroll
            for (int kc = 0; kc < 3; ++kc)
                xv[kr * 3 + kc] = xp[kr * W_ + kc];
#pragma unroll
        for (int co = 0; co < CO; ++co) {
            const float* wp = w + co * (CI * 9) + ci * 9;
            float a = acc[co];
#pragma unroll
            for (int k = 0; k < 9; ++k) a = fmaf(xv[k], wp[k], a);
            acc[co] = a;
        }
    }
    __shared__ float lds[64][65];
    for (int s = 0; s < 4; ++s) {
        if (chunk == s) {
            if (s == 0) {
#pragma unroll
                for (int co = 0; co < CO; ++co) lds[el][co] = acc[co];
            } else {
#pragma unroll
                for (int co = 0; co < CO; ++co) lds[el][co] += acc[co];
            }
        }
        __syncthreads();
    }
    if (chunk == 0 && active) {
#pragma unroll
        for (int co = 0; co < CO; ++co)
            y[(((size_t)b * CO + co) * H_ + r_out) * W_ + c_out] = lds[el][co] + bias[co];
    }
}

__global__ __launch_bounds__(256) void conv_corner(
    const float* __restrict__ x,
    const float* __restrict__ w_bl, const float* __restrict__ w_br,
    const float* __restrict__ w_tl, const float* __restrict__ w_tr,
    const float* __restrict__ bias, float* __restrict__ y)
{
    const int b      = blockIdx.x;
    const int corner = threadIdx.x >> 6;
    const int co     = threadIdx.x & 63;
    const float* w = (corner == 0) ? w_bl : (corner == 1) ? w_br
                   : (corner == 2) ? w_tl : w_tr;
    const int rr    = (corner < 2) ? (H_ - 3) : 0;
    const int cc    = (corner & 1) ? (W_ - 3) : 0;
    const int r_out = (corner < 2) ? 0 : (H_ - 1);
    const int c_out = (corner & 1) ? (W_ - 1) : 0;
    const float* xb = x + (size_t)b * CI * H_ * W_;
    float a = 0.f;
    for (int ci = 0; ci < CI; ++ci) {
        const float* xp = xb + ((size_t)ci * H_ + rr) * W_ + cc;
        const float* wp = w + ((size_t)co * CI + ci) * 9;
#pragma unroll
        for (int kr = 0; kr < 3; ++kr)
#pragma unroll
            for (int kc = 0; kc < 3; ++kc)
                a = fmaf(xp[kr * W_ + kc], wp[kr * 3 + kc], a);
    }
    y[(((size_t)b * CO + co) * H_ + r_out) * W_ + c_out] = a + bias[co];
}

__global__ __launch_bounds__(256) void stats_kernel(
    const float* __restrict__ y, float* __restrict__ ws)
{
    const int bid   = blockIdx.x;
    const int chunk = bid & 3;
    const int g     = (bid >> 2) & 15;
    const int b     = bid >> 6;
    const float* p  = y + ((size_t)(b * 64 + g * 4 + chunk)) * (H_ * W_);
    float s = 0.f, q = 0.f;
    for (int i = threadIdx.x; i < (H_ * W_ / 4); i += 256) {
        float4 v = reinterpret_cast<const float4*>(p)[i];
        s += v.x + v.y + v.z + v.w;
        q += v.x * v.x + v.y * v.y + v.z * v.z + v.w * v.w;
    }
#pragma unroll
    for (int off = 32; off; off >>= 1) {
        s += __shfl_down(s, off);
        q += __shfl_down(q, off);
    }
    __shared__ float red[8];
    const int wid = threadIdx.x >> 6;
    if ((threadIdx.x & 63) == 0) { red[wid * 2] = s; red[wid * 2 + 1] = q; }
    __syncthreads();
    if (threadIdx.x == 0) {
        ws[bid * 2]     = red[0] + red[2] + red[4] + red[6];
        ws[bid * 2 + 1] = red[1] + red[3] + red[5] + red[7];
    }
}

__global__ __launch_bounds__(256) void norm_stats(
    float* __restrict__ y, const float* __restrict__ st,
    const float* __restrict__ gamma, const float* __restrict__ beta)
{
    const size_t t = (size_t)blockIdx.x * 256 + threadIdx.x;
    const size_t e = t * 4;
    const int b  = (int)(e >> 22);
    const int ch = (int)((e >> 16) & 63);
    const int g  = ch >> 2;
    const int sb = ((b * 16 + g) * 4) * 2;
    const float S = st[sb] + st[sb + 2] + st[sb + 4] + st[sb + 6];
    const float Q = st[sb + 1] + st[sb + 3] + st[sb + 5] + st[sb + 7];
    const float inv_n = 1.0f / (4.0f * H_ * W_);
    const float mean  = S * inv_n;
    const float var   = Q * inv_n - mean * mean;
    const float rstd  = rsqrtf(var + EPS_);
    const float ga = gamma[ch] * rstd;
    const float be = beta[ch] - mean * ga;
    float4 v = reinterpret_cast<float4*>(y)[t];
    float u;
    u = v.x * ga + be; v.x = selu_f(u);
    u = v.y * ga + be; v.y = selu_f(u);
    u = v.z * ga + be; v.z = selu_f(u);
    u = v.w * ga + be; v.w = selu_f(u);
    reinterpret_cast<float4*>(y)[t] = v;
}

extern "C" void kernel_launch(void* const* d_in, const int* in_sizes, int n_in,
                              void* d_out, int out_size, void* d_ws, size_t ws_size,
                              hipStream_t stream) {
    const float* x       = (const float*)d_in[0];
    const float* w_int   = (const float*)d_in[1];
    const float* w_tl    = (const float*)d_in[2];
    const float* w_tr    = (const float*)d_in[3];
    const float* w_bl    = (const float*)d_in[4];
    const float* w_br    = (const float*)d_in[5];
    const float* w_top   = (const float*)d_in[6];
    const float* w_bot   = (const float*)d_in[7];
    const float* w_left  = (const float*)d_in[8];
    const float* w_right = (const float*)d_in[9];
    const float* bias    = (const float*)d_in[10];
    const float* gamma   = (const float*)d_in[11];
    const float* beta    = (const float*)d_in[12];

    float* out = (float*)d_out;

    const size_t XPRE  = 67108864ull;                  // bf16 x NHWC
    const size_t YBF   = 67108864ull;                  // bf16 y NCHW
    const size_t WPRE9 = 663552ull;                    // bf16 [9][9][64][64]
    const size_t WEDGE = 1179648ull;                   // fp32 [8][9][16][64][4]
    const size_t PART  = 524288ull;                    // [8][512][16][2] f32
    const size_t MV    = 1024ull;
    const size_t NEED  = XPRE + YBF + WPRE9 + WEDGE + PART + MV;

    if (ws_size >= NEED) {
        char* base = (char*)d_ws;
        unsigned short* xpre  = (unsigned short*)base;  base += XPRE;
        unsigned short* ybf   = (unsigned short*)base;  base += YBF;
        unsigned short* wpre9 = (unsigned short*)base;  base += WPRE9;
        float*          wedge = (float*)base;           base += WEDGE;
        float*          part  = (float*)base;           base += PART;
        float*          mv    = (float*)base;

        prepass_weights<<<dim3(81), 256, 0, stream>>>(
            w_int, w_bl, w_br, w_tl, w_tr, w_bot, w_top, w_left, w_right,
            wpre9, wedge);
        prepass_x<<<dim3(256, 8), 256, 0, stream>>>(x, xpre);
        conv_all<<<dim3(8, 36, 8), 512, 0, stream>>>(
            xpre, wpre9, wedge, bias, ybf, part);
        stats_reduce<<<dim3(8), 256, 0, stream>>>(part, mv);
        norm_bf<<<dim3(16384), 256, 0, stream>>>(ybf, out, mv, gamma, beta);
    } else {
        float* stats = (float*)d_ws;
        conv_main<<<dim3(H_, B_), 256, 0, stream>>>(x, w_int, bias, out);
        conv_edge<<<dim3(B_, 4, 4), 256, 0, stream>>>(x, w_bot, w_top, w_left, w_right, bias, out);
        conv_corner<<<dim3(B_), 256, 0, stream>>>(x, w_bl, w_br, w_tl, w_tr, bias, out);
        stats_kernel<<<dim3(512), 256, 0, stream>>>(out, stats);
        norm_stats<<<dim3(32768), 256, 0, stream>>>(out, stats, gamma, beta);
    }
}

// Round 17
// 168.386 us; speedup vs baseline: 6.8104x; 1.0238x over previous
//
#include <hip/hip_runtime.h>

#define B_ 8
#define CI 64
#define CO 64
#define H_ 256
#define W_ 256
#define EPS_ 1e-5f

#define SELU_SCALE 1.0507009873554805f
#define SELU_SA    1.7580993408473766f

typedef __attribute__((ext_vector_type(8))) short short8;
typedef __attribute__((ext_vector_type(4))) float f32x4;
typedef unsigned int u32;

__device__ __forceinline__ unsigned short f2bf(float f) {
    unsigned int u = __float_as_uint(f);
    u = (u + 0x7fffu + ((u >> 16) & 1u)) >> 16;
    return (unsigned short)u;
}
__device__ __forceinline__ float bf2f(unsigned short h) {
    return __uint_as_float(((unsigned)h) << 16);
}
__device__ __forceinline__ float selu_f(float u) {
    return (u > 0.f) ? SELU_SCALE * u : SELU_SA * (__expf(u) - 1.f);
}
__device__ __forceinline__ void gload_lds16(const void* g, void* l) {
    __builtin_amdgcn_global_load_lds(
        (const __attribute__((address_space(1))) u32*)g,
        (__attribute__((address_space(3))) u32*)l, 16, 0, 0);
}

// ===========================================================================
// Fused prepass: grid 2129 blocks.
//   blk < 2048 : x fp32 NCHW -> bf16 NHWC swizzled (row = blk&255, b = blk>>8)
//   blk >= 2048: weights -> wpre9 bf16 (9 wids x 9 pos) + wedge fp32 (wid<8)
// ===========================================================================
__global__ __launch_bounds__(256) void prepass_fused(
    const float* __restrict__ x,
    const float* __restrict__ w_int,
    const float* __restrict__ w_bl, const float* __restrict__ w_br,
    const float* __restrict__ w_tl, const float* __restrict__ w_tr,
    const float* __restrict__ w_bot, const float* __restrict__ w_top,
    const float* __restrict__ w_left, const float* __restrict__ w_right,
    unsigned short* __restrict__ xpre,
    unsigned short* __restrict__ wpre9, float* __restrict__ wedge)
{
    __shared__ unsigned short ls[256 * 72];
    const int blk = blockIdx.x, t = threadIdx.x;

    if (blk < 2048) {
        const int row = blk & 255, b = blk >> 8;
        const int colq = t >> 2;
        const float* xb = x + ((size_t)(b * 64) * 256 + row) * 256;

        for (int sp = 0; sp < 4; ++sp) {
            const int cibase = sp * 16 + (t & 3) * 4;
            float4 v[4];
#pragma unroll
            for (int e = 0; e < 4; ++e)
                v[e] = *(const float4*)(xb + (size_t)(cibase + e) * 65536 + colq * 4);
#pragma unroll
            for (int jj = 0; jj < 4; ++jj) {
                const int col = colq * 4 + jj;
                const int sw  = (col & 7) << 3;
                ushort4 pk;
                pk.x = f2bf((&v[0].x)[jj]);
                pk.y = f2bf((&v[1].x)[jj]);
                pk.z = f2bf((&v[2].x)[jj]);
                pk.w = f2bf((&v[3].x)[jj]);
                *(ushort4*)&ls[col * 72 + (cibase ^ sw)] = pk;
            }
        }
        __syncthreads();
        unsigned short* xp = xpre + ((size_t)(b * 256 + row)) * 256 * 64;
        for (int q = 0; q < 8; ++q) {
            const int lin = q * 256 + t;
            const int col = lin >> 3, k = lin & 7;
            *(uint4*)(xp + col * 64 + k * 8) = *(const uint4*)&ls[col * 72 + k * 8];
        }
    } else {
        const int wb = blk - 2048;
        const int wid = wb / 9, pos = wb % 9;
        const float* src = (wid == 0) ? w_bl : (wid == 1) ? w_br
                         : (wid == 2) ? w_tl : (wid == 3) ? w_tr
                         : (wid == 4) ? w_bot : (wid == 5) ? w_top
                         : (wid == 6) ? w_left : (wid == 7) ? w_right : w_int;
        for (int k = 0; k < 16; ++k) {
            const int lin = k * 256 + t;
            const int co = lin >> 6, cip = lin & 63;
            const int ci = cip ^ ((co & 7) << 3);
            wpre9[(size_t)wid * 36864 + pos * 4096 + lin] =
                f2bf(src[(co * 64 + ci) * 9 + pos]);
            if (wid < 8) {
                const int c4 = lin >> 8, co2 = (lin >> 2) & 63, j = lin & 3;
                const int ci2 = c4 * 4 + j;
                wedge[(size_t)wid * 36864 + pos * 4096 + lin] =
                    src[(co2 * 64 + ci2) * 9 + pos];
            }
        }
    }
}

// ===========================================================================
// Fused conv: grid (8, 36, 8). (R16 proven)
//   by < 32 : interior MFMA tile, stores only r,c in 1..254.
//   by >= 32: job = (by-32)*8 + bx: 0..15 TB, 16..23 LR, 24 corners.
// Stats partials: interior 0..255, TB 256..271, LR 272..279, corner 280.
// ===========================================================================
__global__ __launch_bounds__(512, 4) void conv_all(
    const unsigned short* __restrict__ xpre, const unsigned short* __restrict__ wpre9,
    const float* __restrict__ wedge, const float* __restrict__ bias,
    unsigned short* __restrict__ ybf, float* __restrict__ part)
{
    __shared__ unsigned short xs[10 * 40 * 64];   // 51200 B (borders alias)
    __shared__ unsigned short wl3[3][4096];       // 12288 B
    __shared__ float sred[8][16][2];              // 1024 B (borders alias)
    const int t = threadIdx.x, w = t >> 6, lane = t & 63;
    const int b = blockIdx.z;
    const int l15 = lane & 15, lg = lane >> 4;
    const int sw15 = (l15 & 7) << 3;

    if (blockIdx.y < 32) {
        // ================= interior =================
        const unsigned short* wpre = wpre9 + 8 * 36864;
        const int r0 = blockIdx.y * 8, c0 = blockIdx.x * 32;

        for (int L = w; L < 50; L += 8) {
            const int j = L / 5, i = L % 5;
            int rr = r0 - 1 + j; rr = rr < 0 ? 0 : (rr > 255 ? 255 : rr);
            int col = c0 - 2 + i * 8 + (lane >> 3);
            col = col < 0 ? 0 : (col > 255 ? 255 : col);
            gload_lds16((const char*)xpre +
                            ((size_t)((b * 256 + rr) * 256 + col)) * 128 + (lane & 7) * 16,
                        (char*)xs + j * 5120 + i * 1024);
        }
        gload_lds16((const char*)wpre + 0 * 8192 + w * 1024 + lane * 16,
                    (char*)wl3[0] + w * 1024);
        gload_lds16((const char*)wpre + 1 * 8192 + w * 1024 + lane * 16,
                    (char*)wl3[1] + w * 1024);

        int jb[3];
#pragma unroll
        for (int kr = 0; kr < 3; ++kr) jb[kr] = (w + kr) * 5120;
        int offb[3][2][2];
#pragma unroll
        for (int kc = 0; kc < 3; ++kc)
#pragma unroll
            for (int n = 0; n < 2; ++n) {
                const int s = n * 16 + l15 + kc + 1;
#pragma unroll
                for (int ks = 0; ks < 2; ++ks) {
                    const int cib = ks * 32 + lg * 8;
                    offb[kc][n][ks] = s * 128 + ((cib ^ (((s + 6) & 7) << 3)) << 1);
                }
            }
        int afo[2][4];
#pragma unroll
        for (int ks = 0; ks < 2; ++ks)
#pragma unroll
            for (int m = 0; m < 4; ++m) {
                const int cib = ks * 32 + lg * 8;
                afo[ks][m] = (m * 16 + l15) * 128 + ((cib ^ sw15) << 1);
            }

        f32x4 acc[4][2];
#pragma unroll
        for (int m = 0; m < 4; ++m)
#pragma unroll
            for (int n = 0; n < 2; ++n)
                acc[m][n] = (f32x4){0.f, 0.f, 0.f, 0.f};

#pragma unroll
        for (int pos = 0; pos < 9; ++pos) {
            if (pos < 8) asm volatile("s_waitcnt vmcnt(1)" ::: "memory");
            else         asm volatile("s_waitcnt vmcnt(0)" ::: "memory");
            __builtin_amdgcn_s_barrier();
            __builtin_amdgcn_sched_barrier(0);
            if (pos + 2 <= 8)
                gload_lds16((const char*)wpre + (pos + 2) * 8192 + w * 1024 + lane * 16,
                            (char*)wl3[(pos + 2) % 3] + w * 1024);
            const int kr = pos / 3, kc = pos % 3;
            const char* wbuf = (const char*)wl3[pos % 3];
#pragma unroll
            for (int ks = 0; ks < 2; ++ks) {
                short8 bf[2], af[4];
#pragma unroll
                for (int n = 0; n < 2; ++n)
                    bf[n] = *(const short8*)((const char*)xs + jb[kr] + offb[kc][n][ks]);
#pragma unroll
                for (int m = 0; m < 4; ++m)
                    af[m] = *(const short8*)(wbuf + afo[ks][m]);
                __builtin_amdgcn_s_setprio(1);
#pragma unroll
                for (int m = 0; m < 4; ++m)
#pragma unroll
                    for (int n = 0; n < 2; ++n)
                        acc[m][n] = __builtin_amdgcn_mfma_f32_16x16x32_bf16(
                            af[m], bf[n], acc[m][n], 0, 0, 0);
                __builtin_amdgcn_s_setprio(0);
            }
        }

        const int r = r0 + w;
        const bool rmask = (r != 0) && (r != 255);
        float s4[4] = {0.f, 0.f, 0.f, 0.f}, q4[4] = {0.f, 0.f, 0.f, 0.f};
#pragma unroll
        for (int m = 0; m < 4; ++m)
#pragma unroll
            for (int n = 0; n < 2; ++n) {
                const int c = c0 + n * 16 + l15;
                const bool pmask = rmask && (c != 0) && (c != 255);
#pragma unroll
                for (int reg = 0; reg < 4; ++reg) {
                    const int co = m * 16 + lg * 4 + reg;
                    const float v = acc[m][n][reg] + bias[co];
                    if (pmask) {
                        ybf[(((size_t)b * 64 + co) * 256 + r) * 256 + c] = f2bf(v);
                        s4[m] += v; q4[m] += v * v;
                    }
                }
            }
#pragma unroll
        for (int off = 1; off < 16; off <<= 1)
#pragma unroll
            for (int m = 0; m < 4; ++m) {
                s4[m] += __shfl_xor(s4[m], off);
                q4[m] += __shfl_xor(q4[m], off);
            }
        if (l15 == 0) {
#pragma unroll
            for (int m = 0; m < 4; ++m) {
                sred[w][m * 4 + lg][0] = s4[m];
                sred[w][m * 4 + lg][1] = q4[m];
            }
        }
        __syncthreads();
        if (t < 32) {
            const int g = t & 15, sel = t >> 4;
            float v = 0.f;
#pragma unroll
            for (int ww = 0; ww < 8; ++ww) v += sred[ww][g][sel];
            const int slot = blockIdx.y * 8 + blockIdx.x;
            part[((size_t)(b * 512 + slot) * 16 + g) * 2 + sel] = v;
        }
        return;
    }

    // ================= borders =================
    const int job = (blockIdx.y - 32) * 8 + blockIdx.x;
    if (job > 24) return;

    if (job < 16) {
        // ---- TB: rows 0 / 255 ----
        const int edge = job >> 3, seg = job & 7;
        const int c0 = seg * 32;
        const char* wsrc = (const char*)wpre9 + (size_t)(4 + edge) * 73728;
        for (int L = w; L < 15; L += 8) {
            const int j = L / 5, i = L % 5;
            const int rr = (edge == 0) ? (253 + j) : j;
            int col = c0 - 2 + i * 8 + (lane >> 3);
            col = col < 0 ? 0 : (col > 255 ? 255 : col);
            gload_lds16((const char*)xpre +
                            ((size_t)((b * 256 + rr) * 256 + col)) * 128 + (lane & 7) * 16,
                        (char*)xs + j * 5120 + i * 1024);
        }
        gload_lds16(wsrc + 0 * 8192 + w * 1024 + lane * 16, (char*)wl3[0] + w * 1024);
        gload_lds16(wsrc + 1 * 8192 + w * 1024 + lane * 16, (char*)wl3[1] + w * 1024);

        const int cot = w & 3, nh = w >> 2;
        int offb2[3][2];
#pragma unroll
        for (int kc = 0; kc < 3; ++kc) {
            const int s = nh * 16 + l15 + kc + 1;
#pragma unroll
            for (int ks = 0; ks < 2; ++ks) {
                const int cib = ks * 32 + lg * 8;
                offb2[kc][ks] = s * 128 + ((cib ^ (((s + 6) & 7) << 3)) << 1);
            }
        }
        int afo2[2];
#pragma unroll
        for (int ks = 0; ks < 2; ++ks) {
            const int cib = ks * 32 + lg * 8;
            afo2[ks] = (cot * 16 + l15) * 128 + ((cib ^ sw15) << 1);
        }
        f32x4 acc0 = (f32x4){0.f, 0.f, 0.f, 0.f};

#pragma unroll
        for (int pos = 0; pos < 9; ++pos) {
            if (pos < 8) asm volatile("s_waitcnt vmcnt(1)" ::: "memory");
            else         asm volatile("s_waitcnt vmcnt(0)" ::: "memory");
            __builtin_amdgcn_s_barrier();
            __builtin_amdgcn_sched_barrier(0);
            if (pos + 2 <= 8)
                gload_lds16(wsrc + (pos + 2) * 8192 + w * 1024 + lane * 16,
                            (char*)wl3[(pos + 2) % 3] + w * 1024);
            const int kr = pos / 3, kc = pos % 3;
            const char* wbuf = (const char*)wl3[pos % 3];
#pragma unroll
            for (int ks = 0; ks < 2; ++ks) {
                const short8 bf = *(const short8*)((const char*)xs + kr * 5120 + offb2[kc][ks]);
                const short8 af = *(const short8*)(wbuf + afo2[ks]);
                acc0 = __builtin_amdgcn_mfma_f32_16x16x32_bf16(af, bf, acc0, 0, 0, 0);
            }
        }

        const int r_out = edge ? 255 : 0;
        const int c = c0 + nh * 16 + l15;
        const bool pmask = (c != 0) && (c != 255);
        float s = 0.f, q = 0.f;
#pragma unroll
        for (int reg = 0; reg < 4; ++reg) {
            const int co = cot * 16 + lg * 4 + reg;
            const float v = acc0[reg] + bias[co];
            if (pmask) {
                ybf[(((size_t)b * 64 + co) * 256 + r_out) * 256 + c] = f2bf(v);
                s += v; q += v * v;
            }
        }
        s += __shfl_xor(s, 1); q += __shfl_xor(q, 1);
        s += __shfl_xor(s, 2); q += __shfl_xor(q, 2);
        s += __shfl_xor(s, 4); q += __shfl_xor(q, 4);
        s += __shfl_xor(s, 8); q += __shfl_xor(q, 8);
        float* sb = (float*)sred;
        if (l15 == 0) { sb[(w * 4 + lg) * 2] = s; sb[(w * 4 + lg) * 2 + 1] = q; }
        __syncthreads();
        if (t < 32) {
            const int g = t & 15, sel = t >> 4;
            const int ct = g >> 2, sub = g & 3;
            const float v = sb[(ct * 4 + sub) * 2 + sel] + sb[((ct + 4) * 4 + sub) * 2 + sel];
            part[((size_t)(b * 512 + 256 + job) * 16 + g) * 2 + sel] = v;
        }
    } else if (job < 24) {
        // ---- LR: cols 0 / 255 ----
        const int jj = job - 16;
        const int edge = jj >> 2, seg = jj & 3;
        const int r0 = seg * 64;
        const int colbase = edge ? 253 : 0;
        unsigned short* xr = xs;                         // 66 rows x 400 B
        for (int u = t; u < 1584; u += 512) {
            const int row = u / 24, rem = u % 24;
            const int cl = rem >> 3, sub = rem & 7;
            int rr = r0 - 1 + row; rr = rr < 0 ? 0 : (rr > 255 ? 255 : rr);
            const int col = colbase + cl;
            const uint4 v = *(const uint4*)(xpre +
                ((size_t)((b * 256 + rr) * 256 + col)) * 64 + sub * 8);
            *(uint4*)((char*)xr + row * 400 + cl * 128 + sub * 16) = v;
        }
        const char* wsrc = (const char*)wpre9 + (size_t)(6 + edge) * 73728;
        gload_lds16(wsrc + 0 * 8192 + w * 1024 + lane * 16, (char*)wl3[0] + w * 1024);
        gload_lds16(wsrc + 1 * 8192 + w * 1024 + lane * 16, (char*)wl3[1] + w * 1024);
        asm volatile("s_waitcnt lgkmcnt(0)" ::: "memory");

        const int cot = w & 3, np = w >> 2;
        int offlr[3][2];
#pragma unroll
        for (int kc = 0; kc < 3; ++kc) {
            const int key = (colbase + kc) & 7;
#pragma unroll
            for (int ks = 0; ks < 2; ++ks) {
                const int cib = ks * 32 + lg * 8;
                offlr[kc][ks] = kc * 128 + ((cib ^ (key << 3)) << 1);
            }
        }
        int rowb2[2];
#pragma unroll
        for (int j = 0; j < 2; ++j) rowb2[j] = ((np * 2 + j) * 16 + l15) * 400;
        int afo2[2];
#pragma unroll
        for (int ks = 0; ks < 2; ++ks) {
            const int cib = ks * 32 + lg * 8;
            afo2[ks] = (cot * 16 + l15) * 128 + ((cib ^ sw15) << 1);
        }
        f32x4 accA = (f32x4){0.f, 0.f, 0.f, 0.f};
        f32x4 accB = (f32x4){0.f, 0.f, 0.f, 0.f};

#pragma unroll
        for (int pos = 0; pos < 9; ++pos) {
            if (pos < 8) asm volatile("s_waitcnt vmcnt(1)" ::: "memory");
            else         asm volatile("s_waitcnt vmcnt(0)" ::: "memory");
            __builtin_amdgcn_s_barrier();
            __builtin_amdgcn_sched_barrier(0);
            if (pos + 2 <= 8)
                gload_lds16(wsrc + (pos + 2) * 8192 + w * 1024 + lane * 16,
                            (char*)wl3[(pos + 2) % 3] + w * 1024);
            const int kr = pos / 3, kc = pos % 3;
            const char* wbuf = (const char*)wl3[pos % 3];
#pragma unroll
            for (int ks = 0; ks < 2; ++ks) {
                const short8 af = *(const short8*)(wbuf + afo2[ks]);
                const short8 bfA = *(const short8*)((const char*)xr + rowb2[0] + kr * 400 + offlr[kc][ks]);
                const short8 bfB = *(const short8*)((const char*)xr + rowb2[1] + kr * 400 + offlr[kc][ks]);
                accA = __builtin_amdgcn_mfma_f32_16x16x32_bf16(af, bfA, accA, 0, 0, 0);
                accB = __builtin_amdgcn_mfma_f32_16x16x32_bf16(af, bfB, accB, 0, 0, 0);
            }
        }

        const int c_out = edge ? 255 : 0;
        float s = 0.f, q = 0.f;
#pragma unroll
        for (int j = 0; j < 2; ++j) {
            const int r = r0 + (np * 2 + j) * 16 + l15;
            const bool pmask = (r != 0) && (r != 255);
            const f32x4 a = j ? accB : accA;
#pragma unroll
            for (int reg = 0; reg < 4; ++reg) {
                const int co = cot * 16 + lg * 4 + reg;
                const float v = a[reg] + bias[co];
                if (pmask) {
                    ybf[(((size_t)b * 64 + co) * 256 + r) * 256 + c_out] = f2bf(v);
                    s += v; q += v * v;
                }
            }
        }
        s += __shfl_xor(s, 1); q += __shfl_xor(q, 1);
        s += __shfl_xor(s, 2); q += __shfl_xor(q, 2);
        s += __shfl_xor(s, 4); q += __shfl_xor(q, 4);
        s += __shfl_xor(s, 8); q += __shfl_xor(q, 8);
        float* sb = (float*)sred;
        if (l15 == 0) { sb[(w * 4 + lg) * 2] = s; sb[(w * 4 + lg) * 2 + 1] = q; }
        __syncthreads();
        if (t < 32) {
            const int g = t & 15, sel = t >> 4;
            const int ct = g >> 2, sub = g & 3;
            const float v = sb[(ct * 4 + sub) * 2 + sel] + sb[((ct + 4) * 4 + sub) * 2 + sel];
            part[((size_t)(b * 512 + 272 + jj) * 16 + g) * 2 + sel] = v;
        }
    } else {
        // ---- corners (job 24) ----
        float* cred = (float*)sred;                      // [4][16][2]
        if (w < 4) {
            const int corner = w, co = lane;
            const int row0 = (corner < 2) ? 253 : 0;
            const int col0 = (corner & 1) ? 253 : 0;
            const int r_out = (corner < 2) ? 0 : 255;
            const int c_out = (corner & 1) ? 255 : 0;
            const float* wbase = wedge + (size_t)corner * 36864;
            float a0 = 0.f, a1 = 0.f, a2 = 0.f, a3 = 0.f;
#pragma unroll 1
            for (int pos = 0; pos < 9; ++pos) {
                const int kr = pos / 3, kc = pos % 3;
                const int row = row0 + kr, col = col0 + kc;
                const unsigned short* xp = xpre + ((size_t)((b * 256 + row) * 256 + col)) * 64;
                const int sw = (col & 7) << 3;
#pragma unroll
                for (int c4 = 0; c4 < 16; ++c4) {
                    const float4 wv = *(const float4*)(wbase + pos * 4096 + c4 * 256 + co * 4);
                    const ushort4 xv = *(const ushort4*)(xp + ((c4 * 4) ^ sw));
                    a0 = fmaf(wv.x, bf2f(xv.x), a0);
                    a1 = fmaf(wv.y, bf2f(xv.y), a1);
                    a2 = fmaf(wv.z, bf2f(xv.z), a2);
                    a3 = fmaf(wv.w, bf2f(xv.w), a3);
                }
            }
            const float v = (a0 + a1) + (a2 + a3) + bias[co];
            ybf[(((size_t)b * 64 + co) * 256 + r_out) * 256 + c_out] = f2bf(v);
            float s = v, q = v * v;
            s += __shfl_xor(s, 1); q += __shfl_xor(q, 1);
            s += __shfl_xor(s, 2); q += __shfl_xor(q, 2);
            if ((co & 3) == 0) {
                cred[(corner * 16 + (co >> 2)) * 2]     = s;
                cred[(corner * 16 + (co >> 2)) * 2 + 1] = q;
            }
        }
        __syncthreads();
        if (t < 32) {
            const int g = t & 15, sel = t >> 4;
            const float r = cred[(0 * 16 + g) * 2 + sel] + cred[(1 * 16 + g) * 2 + sel] +
                            cred[(2 * 16 + g) * 2 + sel] + cred[(3 * 16 + g) * 2 + sel];
            part[((size_t)(b * 512 + 280) * 16 + g) * 2 + sel] = r;
        }
    }
}

// ===========================================================================
// GroupNorm + SELU with inlined stats: each block covers exactly one (b,g);
// it reduces the 281 partial slots itself (redundant across blocks, L2-hot),
// then normalizes 2048 elements (8/thread). Removes the stats_reduce launch.
// ===========================================================================
__global__ __launch_bounds__(256) void norm_bf2(
    const unsigned short* __restrict__ ybf, float* __restrict__ out,
    const float* __restrict__ part,
    const float* __restrict__ gamma, const float* __restrict__ beta)
{
    __shared__ float wred[4][2];
    __shared__ float mvs[2];
    const int t = threadIdx.x;
    const size_t e0 = (size_t)blockIdx.x * 2048;
    const int b  = (int)(e0 >> 22);
    const int ch = (int)((e0 >> 16) & 63);
    const int g  = ch >> 2;

    // ---- inline stats over 281 slots
    float s = 0.f, q = 0.f;
    for (int slot = t; slot < 281; slot += 256) {
        const size_t base = ((size_t)(b * 512 + slot) * 16 + g) * 2;
        s += part[base]; q += part[base + 1];
    }
#pragma unroll
    for (int off = 32; off; off >>= 1) {
        s += __shfl_down(s, off);
        q += __shfl_down(q, off);
    }
    if ((t & 63) == 0) { wred[t >> 6][0] = s; wred[t >> 6][1] = q; }
    __syncthreads();
    if (t == 0) {
        const float S = wred[0][0] + wred[1][0] + wred[2][0] + wred[3][0];
        const float Q = wred[0][1] + wred[1][1] + wred[2][1] + wred[3][1];
        const float inv_n = 1.0f / (4.0f * 65536.0f);
        const float mean = S * inv_n;
        const float var  = Q * inv_n - mean * mean;
        mvs[0] = mean;
        mvs[1] = rsqrtf(var + EPS_);
    }
    __syncthreads();
    const float mean = mvs[0], rstd = mvs[1];
    const float ga = gamma[ch] * rstd;
    const float be = beta[ch] - mean * ga;

    const size_t e = e0 + (size_t)t * 8;
    const uint4 v = *(const uint4*)(ybf + e);
    float f[8];
    f[0] = __uint_as_float(v.x << 16); f[1] = __uint_as_float(v.x & 0xffff0000u);
    f[2] = __uint_as_float(v.y << 16); f[3] = __uint_as_float(v.y & 0xffff0000u);
    f[4] = __uint_as_float(v.z << 16); f[5] = __uint_as_float(v.z & 0xffff0000u);
    f[6] = __uint_as_float(v.w << 16); f[7] = __uint_as_float(v.w & 0xffff0000u);
    float4 o0, o1;
    o0.x = selu_f(f[0] * ga + be); o0.y = selu_f(f[1] * ga + be);
    o0.z = selu_f(f[2] * ga + be); o0.w = selu_f(f[3] * ga + be);
    o1.x = selu_f(f[4] * ga + be); o1.y = selu_f(f[5] * ga + be);
    o1.z = selu_f(f[6] * ga + be); o1.w = selu_f(f[7] * ga + be);
    *(float4*)(out + e)     = o0;
    *(float4*)(out + e + 4) = o1;
}

// ===========================================================================
// Fallback path (round-1 proven kernels) for small ws.
// ===========================================================================
__global__ __launch_bounds__(256) void conv_main(
    const float* __restrict__ x, const float* __restrict__ w,
    const float* __restrict__ bias, float* __restrict__ y)
{
    const int c = threadIdx.x;
    const int r = blockIdx.x;
    const int b = blockIdx.y;
    const int rr = (r == 0) ? (H_ - 3) : ((r == H_ - 1) ? 0 : (r - 1));
    const int cc = min(max(c - 1, 0), W_ - 3);
    float acc[CO];
#pragma unroll
    for (int co = 0; co < CO; ++co) acc[co] = 0.f;
    const float* xb = x + (size_t)b * CI * H_ * W_;
    for (int ci = 0; ci < CI; ++ci) {
        const float* xp = xb + ((size_t)ci * H_ + rr) * W_ + cc;
        float xv[9];
#pragma unroll
        for (int kr = 0; kr < 3; ++kr)
#pragma unroll
            for (int kc = 0; kc < 3; ++kc)
                xv[kr * 3 + kc] = xp[kr * W_ + kc];
        const float* wci = w + ci * 9;
#pragma unroll
        for (int co = 0; co < CO; ++co) {
            const float* wp = wci + co * (CI * 9);
            float a = acc[co];
#pragma unroll
            for (int k = 0; k < 9; ++k) a = fmaf(xv[k], wp[k], a);
            acc[co] = a;
        }
    }
#pragma unroll
    for (int co = 0; co < CO; ++co)
        y[(((size_t)b * CO + co) * H_ + r) * W_ + c] = acc[co] + bias[co];
}

__global__ __launch_bounds__(256) void conv_edge(
    const float* __restrict__ x,
    const float* __restrict__ w_bot, const float* __restrict__ w_top,
    const float* __restrict__ w_left, const float* __restrict__ w_right,
    const float* __restrict__ bias, float* __restrict__ y)
{
    const int b     = blockIdx.x;
    const int edge  = blockIdx.y;
    const int seg   = blockIdx.z;
    const int el    = threadIdx.x & 63;
    const int chunk = threadIdx.x >> 6;
    const int e     = seg * 64 + el;
    const bool active = (e < 254);
    const int ec    = active ? e : 253;
    const float* w = (edge == 0) ? w_bot : (edge == 1) ? w_top
                   : (edge == 2) ? w_left : w_right;
    int r_out, c_out, rr, cc;
    if (edge == 0)      { r_out = 0;      c_out = 1 + ec; rr = H_ - 3; cc = ec; }
    else if (edge == 1) { r_out = H_ - 1; c_out = 1 + ec; rr = 0;      cc = ec; }
    else if (edge == 2) { r_out = 1 + ec; c_out = 0;      rr = ec;     cc = 0; }
    else                { r_out = 1 + ec; c_out = W_ - 1; rr = ec;     cc = W_ - 3; }
    float acc[CO];
#pragma unroll
    for (int co = 0; co < CO; ++co) acc[co] = 0.f;
    const float* xb = x + (size_t)b * CI * H_ * W_;
    const int ci0 = chunk * 16;
    for (int ci = ci0; ci < ci0 + 16; ++ci) {
        const float* xp = xb + ((size_t)ci * H_ + rr) * W_ + cc;
        float xv[9];
#pragma unroll
        for (int kr = 0; kr < 3; ++kr)
#pragma unroll
            for (int kc = 0; kc < 3; ++kc)
                xv[kr * 3 + kc] = xp[kr * W_ + kc];
#pragma unroll
        for (int co = 0; co < CO; ++co) {
            const float* wp = w + co * (CI * 9) + ci * 9;
            float a = acc[co];
#pragma unroll
            for (int k = 0; k < 9; ++k) a = fmaf(xv[k], wp[k], a);
            acc[co] = a;
        }
    }
    __shared__ float lds[64][65];
    for (int s = 0; s < 4; ++s) {
        if (chunk == s) {
            if (s == 0) {
#pragma unroll
                for (int co = 0; co < CO; ++co) lds[el][co] = acc[co];
            } else {
#pragma unroll
                for (int co = 0; co < CO; ++co) lds[el][co] += acc[co];
            }
        }
        __syncthreads();
    }
    if (chunk == 0 && active) {
#pragma unroll
        for (int co = 0; co < CO; ++co)
            y[(((size_t)b * CO + co) * H_ + r_out) * W_ + c_out] = lds[el][co] + bias[co];
    }
}

__global__ __launch_bounds__(256) void conv_corner(
    const float* __restrict__ x,
    const float* __restrict__ w_bl, const float* __restrict__ w_br,
    const float* __restrict__ w_tl, const float* __restrict__ w_tr,
    const float* __restrict__ bias, float* __restrict__ y)
{
    const int b      = blockIdx.x;
    const int corner = threadIdx.x >> 6;
    const int co     = threadIdx.x & 63;
    const float* w = (corner == 0) ? w_bl : (corner == 1) ? w_br
                   : (corner == 2) ? w_tl : w_tr;
    const int rr    = (corner < 2) ? (H_ - 3) : 0;
    const int cc    = (corner & 1) ? (W_ - 3) : 0;
    const int r_out = (corner < 2) ? 0 : (H_ - 1);
    const int c_out = (corner & 1) ? (W_ - 1) : 0;
    const float* xb = x + (size_t)b * CI * H_ * W_;
    float a = 0.f;
    for (int ci = 0; ci < CI; ++ci) {
        const float* xp = xb + ((size_t)ci * H_ + rr) * W_ + cc;
        const float* wp = w + ((size_t)co * CI + ci) * 9;
#pragma unroll
        for (int kr = 0; kr < 3; ++kr)
#pragma unroll
            for (int kc = 0; kc < 3; ++kc)
                a = fmaf(xp[kr * W_ + kc], wp[kr * 3 + kc], a);
    }
    y[(((size_t)b * CO + co) * H_ + r_out) * W_ + c_out] = a + bias[co];
}

__global__ __launch_bounds__(256) void stats_kernel(
    const float* __restrict__ y, float* __restrict__ ws)
{
    const int bid   = blockIdx.x;
    const int chunk = bid & 3;
    const int g     = (bid >> 2) & 15;
    const int b     = bid >> 6;
    const float* p  = y + ((size_t)(b * 64 + g * 4 + chunk)) * (H_ * W_);
    float s = 0.f, q = 0.f;
    for (int i = threadIdx.x; i < (H_ * W_ / 4); i += 256) {
        float4 v = reinterpret_cast<const float4*>(p)[i];
        s += v.x + v.y + v.z + v.w;
        q += v.x * v.x + v.y * v.y + v.z * v.z + v.w * v.w;
    }
#pragma unroll
    for (int off = 32; off; off >>= 1) {
        s += __shfl_down(s, off);
        q += __shfl_down(q, off);
    }
    __shared__ float red[8];
    const int wid = threadIdx.x >> 6;
    if ((threadIdx.x & 63) == 0) { red[wid * 2] = s; red[wid * 2 + 1] = q; }
    __syncthreads();
    if (threadIdx.x == 0) {
        ws[bid * 2]     = red[0] + red[2] + red[4] + red[6];
        ws[bid * 2 + 1] = red[1] + red[3] + red[5] + red[7];
    }
}

__global__ __launch_bounds__(256) void norm_stats(
    float* __restrict__ y, const float* __restrict__ st,
    const float* __restrict__ gamma, const float* __restrict__ beta)
{
    const size_t t = (size_t)blockIdx.x * 256 + threadIdx.x;
    const size_t e = t * 4;
    const int b  = (int)(e >> 22);
    const int ch = (int)((e >> 16) & 63);
    const int g  = ch >> 2;
    const int sb = ((b * 16 + g) * 4) * 2;
    const float S = st[sb] + st[sb + 2] + st[sb + 4] + st[sb + 6];
    const float Q = st[sb + 1] + st[sb + 3] + st[sb + 5] + st[sb + 7];
    const float inv_n = 1.0f / (4.0f * H_ * W_);
    const float mean  = S * inv_n;
    const float var   = Q * inv_n - mean * mean;
    const float rstd  = rsqrtf(var + EPS_);
    const float ga = gamma[ch] * rstd;
    const float be = beta[ch] - mean * ga;
    float4 v = reinterpret_cast<float4*>(y)[t];
    float u;
    u = v.x * ga + be; v.x = selu_f(u);
    u = v.y * ga + be; v.y = selu_f(u);
    u = v.z * ga + be; v.z = selu_f(u);
    u = v.w * ga + be; v.w = selu_f(u);
    reinterpret_cast<float4*>(y)[t] = v;
}

extern "C" void kernel_launch(void* const* d_in, const int* in_sizes, int n_in,
                              void* d_out, int out_size, void* d_ws, size_t ws_size,
                              hipStream_t stream) {
    const float* x       = (const float*)d_in[0];
    const float* w_int   = (const float*)d_in[1];
    const float* w_tl    = (const float*)d_in[2];
    const float* w_tr    = (const float*)d_in[3];
    const float* w_bl    = (const float*)d_in[4];
    const float* w_br    = (const float*)d_in[5];
    const float* w_top   = (const float*)d_in[6];
    const float* w_bot   = (const float*)d_in[7];
    const float* w_left  = (const float*)d_in[8];
    const float* w_right = (const float*)d_in[9];
    const float* bias    = (const float*)d_in[10];
    const float* gamma   = (const float*)d_in[11];
    const float* beta    = (const float*)d_in[12];

    float* out = (float*)d_out;

    const size_t XPRE  = 67108864ull;                  // bf16 x NHWC
    const size_t YBF   = 67108864ull;                  // bf16 y NCHW
    const size_t WPRE9 = 663552ull;                    // bf16 [9][9][64][64]
    const size_t WEDGE = 1179648ull;                   // fp32 [8][9][16][64][4]
    const size_t PART  = 524288ull;                    // [8][512][16][2] f32
    const size_t NEED  = XPRE + YBF + WPRE9 + WEDGE + PART;

    if (ws_size >= NEED) {
        char* base = (char*)d_ws;
        unsigned short* xpre  = (unsigned short*)base;  base += XPRE;
        unsigned short* ybf   = (unsigned short*)base;  base += YBF;
        unsigned short* wpre9 = (unsigned short*)base;  base += WPRE9;
        float*          wedge = (float*)base;           base += WEDGE;
        float*          part  = (float*)base;

        prepass_fused<<<dim3(2129), 256, 0, stream>>>(
            x, w_int, w_bl, w_br, w_tl, w_tr, w_bot, w_top, w_left, w_right,
            xpre, wpre9, wedge);
        conv_all<<<dim3(8, 36, 8), 512, 0, stream>>>(
            xpre, wpre9, wedge, bias, ybf, part);
        norm_bf2<<<dim3(16384), 256, 0, stream>>>(ybf, out, part, gamma, beta);
    } else {
        float* stats = (float*)d_ws;
        conv_main<<<dim3(H_, B_), 256, 0, stream>>>(x, w_int, bias, out);
        conv_edge<<<dim3(B_, 4, 4), 256, 0, stream>>>(x, w_bot, w_top, w_left, w_right, bias, out);
        conv_corner<<<dim3(B_), 256, 0, stream>>>(x, w_bl, w_br, w_tl, w_tr, bias, out);
        stats_kernel<<<dim3(512), 256, 0, stream>>>(out, stats);
        norm_stats<<<dim3(32768), 256, 0, stream>>>(out, stats, gamma, beta);
    }
}